// Round 13
// baseline (87.899 us; speedup 1.0000x reference)
//
#include <hip/hip_runtime.h>
#include <hip/hip_bf16.h>
#include <stdint.h>

// Problem constants
#define B_    2
#define S_    2048
#define H_    16
#define DH_   64
#define D_    1024
#define ND3   3072      // 3*D
#define MTOT  4096      // B*S
#define L2E   1.4426950408889634f
#define MASKVAL (-3.0e38f)   // causal mask: exp2(MASKVAL) == 0
#define SBIAS   (-14.0f)     // static softmax offset (log2 units), folded
                             // into the QK MFMA C-init (constant C register).

typedef __attribute__((ext_vector_type(8))) short bf16x8;
typedef __attribute__((ext_vector_type(4))) short bf16x4;
typedef __attribute__((ext_vector_type(4))) float f32x4;

__device__ inline short f2bs(float f) {
  __hip_bfloat16 h = __float2bfloat16(f);
  return *reinterpret_cast<short*>(&h);
}

__device__ inline void gl_lds16(const void* g, void* l) {
  __builtin_amdgcn_global_load_lds(
      (const __attribute__((address_space(1))) uint32_t*)g,
      (__attribute__((address_space(3))) uint32_t*)l, 16, 0, 0);
}

// --------------------------------------- fused prep: x->bf16 and W->Wt bf16
__global__ __launch_bounds__(256) void prep_kernel(
    const float* __restrict__ X, const float* __restrict__ Wq,
    const float* __restrict__ Wk, const float* __restrict__ Wv,
    short* __restrict__ Xb, short* __restrict__ Wt) {
  __shared__ float t[32][33];
  int bid = blockIdx.x;
  if (bid < 4096) {
    const int i = (bid * 256 + threadIdx.x) * 4;
    float4 v = *reinterpret_cast<const float4*>(X + i);
    bf16x4 o;
    o[0] = f2bs(v.x); o[1] = f2bs(v.y); o[2] = f2bs(v.z); o[3] = f2bs(v.w);
    *reinterpret_cast<bf16x4*>(Xb + i) = o;
  } else {
    bid -= 4096;
    const int z = bid >> 10;             // 0..2 : Wq/Wk/Wv
    const int rem = bid & 1023;
    const int n0 = (rem & 31) * 32, k0 = (rem >> 5) * 32;
    const int x = threadIdx.x & 31, y = threadIdx.x >> 5;   // y in 0..7
    const float* W = z == 0 ? Wq : (z == 1 ? Wk : Wv);
    short* out = Wt + (size_t)z * (D_ * D_);
#pragma unroll
    for (int i = 0; i < 4; ++i)
      t[y + 8 * i][x] = W[(size_t)(k0 + y + 8 * i) * D_ + n0 + x];
    __syncthreads();
#pragma unroll
    for (int i = 0; i < 4; ++i)
      out[(size_t)(n0 + y + 8 * i) * D_ + k0 + x] = f2bs(t[x][y + 8 * i]);
  }
}

// ---------------------------------------------------------------- QKV GEMM
// Q/K blocks (n0 < 2D): write bf16 into qkv rows (Q pre-scaled by 0.125*L2E).
// V blocks (n0 >= 2D): write DIRECTLY into Vt[bh][dh][s] (fused transpose).
__global__ __launch_bounds__(256, 3) void qkv_gemm_kernel(
    const short* __restrict__ Xb, const short* __restrict__ Wt,
    const float* __restrict__ bq, const float* __restrict__ bk,
    const float* __restrict__ bv, short* __restrict__ QKV,
    short* __restrict__ Vt) {
  __shared__ short As[128 * 64];
  __shared__ short Bs[128 * 64];
  const int tid = threadIdx.x;
  const int lane = tid & 63, wid = tid >> 6;
  const int l15 = lane & 15, lg = lane >> 4;
  const int m0 = blockIdx.x * 128, n0 = blockIdx.y * 128;
  const int wr = (wid >> 1) * 64, wc = (wid & 1) * 64;

  f32x4 acc[4][4];
#pragma unroll
  for (int i = 0; i < 4; ++i)
#pragma unroll
    for (int j = 0; j < 4; ++j) acc[i][j] = (f32x4){0.f, 0.f, 0.f, 0.f};

  for (int k0 = 0; k0 < D_; k0 += 64) {
    __syncthreads();
#pragma unroll
    for (int it = 0; it < 4; ++it) {
      const int e = (it * 256 + tid) * 8;
      const int row = e >> 6, kk = e & 63;
      const int lb = (it * 256 + (tid & 192)) * 16;
      gl_lds16(Xb + (size_t)(m0 + row) * D_ + k0 + kk, (char*)As + lb);
      gl_lds16(Wt + (size_t)(n0 + row) * D_ + k0 + kk, (char*)Bs + lb);
    }
    __syncthreads();
#pragma unroll
    for (int ks = 0; ks < 2; ++ks) {
      bf16x8 a[4], b[4];
#pragma unroll
      for (int mt = 0; mt < 4; ++mt)
        a[mt] = *reinterpret_cast<const bf16x8*>(
            &As[(wr + mt * 16 + l15) * 64 + ks * 32 + lg * 8]);
#pragma unroll
      for (int nt = 0; nt < 4; ++nt)
        b[nt] = *reinterpret_cast<const bf16x8*>(
            &Bs[(wc + nt * 16 + l15) * 64 + ks * 32 + lg * 8]);
#pragma unroll
      for (int mt = 0; mt < 4; ++mt)
#pragma unroll
        for (int nt = 0; nt < 4; ++nt)
          acc[mt][nt] = __builtin_amdgcn_mfma_f32_16x16x32_bf16(
              a[mt], b[nt], acc[mt][nt], 0, 0, 0);
    }
  }
  if (n0 < 2 * D_) {  // Q or K -> qkv rows
#pragma unroll
    for (int nt = 0; nt < 4; ++nt) {
      const int col = n0 + wc + nt * 16 + l15;
      float bias, qs;
      if (col < D_) { bias = bq[col];      qs = 0.125f * L2E; }
      else          { bias = bk[col - D_]; qs = 1.f; }
#pragma unroll
      for (int mt = 0; mt < 4; ++mt)
#pragma unroll
        for (int r = 0; r < 4; ++r) {
          const int row = m0 + wr + mt * 16 + lg * 4 + r;
          QKV[(size_t)row * ND3 + col] = f2bs((acc[mt][nt][r] + bias) * qs);
        }
    }
  } else {  // V -> Vt[bh][dh][s] directly (fused transpose)
    const int bb = m0 >> 11;           // batch (2048 rows each)
    const int srow_base = (m0 & 2047) + wr + lg * 4;
#pragma unroll
    for (int nt = 0; nt < 4; ++nt) {
      const int f = n0 + wc + nt * 16 + l15 - 2 * D_;  // v-feature 0..1023
      const float bias = bv[f];
      short* vout =
          Vt + ((size_t)(bb * H_ + (f >> 6)) * DH_ + (f & 63)) * S_;
#pragma unroll
      for (int mt = 0; mt < 4; ++mt) {
        bf16x4 pv;
#pragma unroll
        for (int r = 0; r < 4; ++r) pv[r] = f2bs(acc[mt][nt][r] + bias);
        *reinterpret_cast<bf16x4*>(vout + srow_base + mt * 16) = pv;
      }
    }
  }
}

// ----------------------------------------------------------- flash attention
// r13: issue-count reduction on the r12 structure.
//  - QK C-init from a CONSTANT register (no per-step v_mov of SBIAS).
//  - P pack via v_perm_b32 (1 op/word instead of shr+and+or).
//  - Compile-time buffer offsets (loop unrolled x2 -> parity is static).
//  - 2K+2V LDS slots (32KB): K staged 2 ahead, V 1 ahead -> 5 blocks/CU.
__global__ __launch_bounds__(256, 5) void attn_kernel(
    const short* __restrict__ QKV, const short* __restrict__ Vtg,
    float* __restrict__ Out) {
  __shared__ short KV[4][4096];   // 32KB: K slots @0,8192; V slots @16384,24576
  const int tid = threadIdx.x;
  const int lane = tid & 63, wid = tid >> 6;
  const int l15 = lane & 15, lg = lane >> 4;
  const int bh = blockIdx.x;
  const int qt = (S_ / 64 - 1) - (int)blockIdx.y;   // LPT: longest first
  const int b = bh >> 4, h = bh & 15;
  const int q0 = qt * 64;
  const short* Qg = QKV + (size_t)b * S_ * ND3 + h * DH_;
  const short* Kg = QKV + (size_t)b * S_ * ND3 + D_ + h * DH_;
  const short* Vg = Vtg + (size_t)bh * DH_ * S_;

  // ---- hoisted addressing ----
  const int srow = tid >> 3;
  const int scol = ((tid & 7) ^ (srow & 7)) * 8;   // XOR-swizzled source chunk
  const char* kbase = (const char*)&KV[0][0];
  char* dst = (char*)kbase + (tid & 192) * 16;     // staging lane base
  int ka[2];
#pragma unroll
  for (int ks = 0; ks < 2; ++ks)
    ka[ks] = l15 * 128 + ((((ks * 4 + lg)) ^ (l15 & 7)) << 4);
  int va[4];
#pragma unroll
  for (int ntk = 0; ntk < 4; ++ntk)
    va[ntk] = l15 * 128 + (((2 * ntk + (lg >> 1)) ^ (l15 & 7)) << 4) +
              ((lg & 1) << 3);
  const int qrow_g = q0 + wid * 16 + l15;

  bf16x8 qf[2];
#pragma unroll
  for (int ks = 0; ks < 2; ++ks)
    qf[ks] = *reinterpret_cast<const bf16x8*>(Qg + (size_t)qrow_g * ND3 +
                                              ks * 32 + lg * 8);

  const f32x4 cinit = (f32x4){SBIAS, SBIAS, SBIAS, SBIAS};  // constant C reg

  f32x4 o[4];
#pragma unroll
  for (int i = 0; i < 4; ++i) o[i] = (f32x4){0.f, 0.f, 0.f, 0.f};
  float lsum = 0.f;   // per-lane partial; uniform scale cancels in O/lsum

  const short* kp = Kg + (size_t)srow * ND3 + scol;
  const short* vp = Vg + (size_t)srow * S_ + scol;

#define STAGE_K(KOFF)                                                         \
  {                                                                           \
    gl_lds16(kp, dst + (KOFF));                                               \
    gl_lds16(kp + 32 * ND3, dst + (KOFF) + 4096);                             \
    kp += 64 * ND3;                                                           \
  }
#define STAGE_V(VOFF)                                                         \
  {                                                                           \
    gl_lds16(vp, dst + (VOFF));                                               \
    gl_lds16(vp + 32 * S_, dst + (VOFF) + 4096);                              \
    vp += 64;                                                                 \
  }

  // prologue: K(0)->slot0, K(1)->slot1, V(0)->slot0; drain; QK(0); barrier.
  STAGE_K(0);
  STAGE_V(16384);
  if (qt >= 1) STAGE_K(8192);
  asm volatile("s_waitcnt vmcnt(0)" ::: "memory");
  __builtin_amdgcn_s_barrier();
  __builtin_amdgcn_sched_barrier(0);

  f32x4 sA[4], sB[4];
#pragma unroll
  for (int nt = 0; nt < 4; ++nt)
    sA[nt] = __builtin_amdgcn_mfma_f32_16x16x32_bf16(
        *reinterpret_cast<const bf16x8*>(kbase + ka[0] + nt * 2048), qf[0],
        cinit, 0, 0, 0);
#pragma unroll
  for (int nt = 0; nt < 4; ++nt)
    sA[nt] = __builtin_amdgcn_mfma_f32_16x16x32_bf16(
        *reinterpret_cast<const bf16x8*>(kbase + ka[1] + nt * 2048), qf[1],
        sA[nt], 0, 0, 0);
  __builtin_amdgcn_s_barrier();   // protect K slot0 / V slot0 from step-0 writes
  __builtin_amdgcn_sched_barrier(0);

// One pipeline step at compile-time parity: softmax+PV on tile T (V at VR),
// QK of T+1 (K at KR) into SN, stage K(T+2)->KW and V(T+1)->VW.
#define STEP_BODY(T, SC, SN, KR, KW, VR, VW)                                  \
  {                                                                           \
    const int T_ = (T);                                                       \
    if (T_ + 2 <= qt) STAGE_K(KW);                                            \
    if (T_ + 1 <= qt) {                                                       \
      STAGE_V(VW);                                                            \
      _Pragma("unroll") for (int nt = 0; nt < 4; ++nt)                        \
          SN[nt] = __builtin_amdgcn_mfma_f32_16x16x32_bf16(                   \
              *reinterpret_cast<const bf16x8*>(kbase + (KR) + ka[0] +         \
                                               nt * 2048),                    \
              qf[0], cinit, 0, 0, 0);                                         \
      _Pragma("unroll") for (int nt = 0; nt < 4; ++nt)                        \
          SN[nt] = __builtin_amdgcn_mfma_f32_16x16x32_bf16(                   \
              *reinterpret_cast<const bf16x8*>(kbase + (KR) + ka[1] +         \
                                               nt * 2048),                    \
              qf[1], SN[nt], 0, 0, 0);                                        \
    }                                                                         \
    if (T_ == qt) { /* causal mask on diagonal tile */                        \
      const int kv0 = T_ * 64;                                                \
      _Pragma("unroll") for (int nt = 0; nt < 4; ++nt)                        \
        _Pragma("unroll") for (int r = 0; r < 4; ++r)                         \
          if (kv0 + nt * 16 + lg * 4 + r > qrow_g) SC[nt][r] = MASKVAL;       \
    }                                                                         \
    float rowsum = 0.f;                                                       \
    bf16x4 pk[4];                                                             \
    _Pragma("unroll") for (int nt = 0; nt < 4; ++nt) {                        \
      const float p0 = exp2f(SC[nt][0]);                                      \
      const float p1 = exp2f(SC[nt][1]);                                      \
      const float p2 = exp2f(SC[nt][2]);                                      \
      const float p3 = exp2f(SC[nt][3]);                                      \
      rowsum += (p0 + p1) + (p2 + p3);                                        \
      union { uint32_t u[2]; bf16x4 v; } pu;                                  \
      pu.u[0] = __builtin_amdgcn_perm(__float_as_uint(p1),                    \
                                      __float_as_uint(p0), 0x07060302u);      \
      pu.u[1] = __builtin_amdgcn_perm(__float_as_uint(p3),                    \
                                      __float_as_uint(p2), 0x07060302u);      \
      pk[nt] = pu.v;                                                          \
    }                                                                         \
    lsum += rowsum;                                                           \
    _Pragma("unroll") for (int ntk = 0; ntk < 4; ++ntk)                       \
      _Pragma("unroll") for (int ntd = 0; ntd < 4; ++ntd) {                   \
        const bf16x4 vf = *reinterpret_cast<const bf16x4*>(                   \
            kbase + (VR) + va[ntk] + ntd * 2048);                             \
        o[ntd] = __builtin_amdgcn_mfma_f32_16x16x16bf16_1k(vf, pk[ntk],       \
                                                           o[ntd], 0, 0, 0);  \
      }                                                                       \
    if (T_ < qt) {                                                            \
      asm volatile("s_waitcnt vmcnt(0)" ::: "memory");                        \
      __builtin_amdgcn_s_barrier();                                           \
      __builtin_amdgcn_sched_barrier(0);                                      \
    }                                                                         \
  }

  for (int t = 0; t <= qt; t += 2) {
    // even step: QK(t+1) from K slot1, PV(t) from V slot0
    STEP_BODY(t, sA, sB, /*KR*/ 8192, /*KW*/ 0, /*VR*/ 16384, /*VW*/ 24576);
    // odd step: mirrored
    if (t + 1 <= qt)
      STEP_BODY(t + 1, sB, sA, /*KR*/ 0, /*KW*/ 8192, /*VR*/ 24576,
                /*VW*/ 16384);
  }
#undef STEP_BODY
#undef STAGE_K
#undef STAGE_V

  // epilogue: sum the 4 per-lane lsum partials of each row, normalize, store.
  float ls = lsum;
  ls += __shfl_xor(ls, 16);
  ls += __shfl_xor(ls, 32);
  const float inv = 1.f / ls;
#pragma unroll
  for (int nt = 0; nt < 4; ++nt) {
    f32x4 v = {o[nt][0] * inv, o[nt][1] * inv, o[nt][2] * inv, o[nt][3] * inv};
    *reinterpret_cast<f32x4*>(
        &Out[((size_t)b * S_ + qrow_g) * D_ + h * DH_ + nt * 16 + lg * 4]) = v;
  }
}

// ---------------------------------------------------------------- launcher
extern "C" void kernel_launch(void* const* d_in, const int* in_sizes, int n_in,
                              void* d_out, int out_size, void* d_ws,
                              size_t ws_size, hipStream_t stream) {
  const float* x  = (const float*)d_in[0];
  const float* Wq = (const float*)d_in[1];
  const float* bq = (const float*)d_in[2];
  const float* Wk = (const float*)d_in[3];
  const float* bk = (const float*)d_in[4];
  const float* Wv = (const float*)d_in[5];
  const float* bv = (const float*)d_in[6];
  float* out = (float*)d_out;

  char* ws = (char*)d_ws;
  short* xb  = (short*)(ws);             //  8 MB: [4096][1024] bf16
  short* Wt  = (short*)(ws + 8388608);   //  6 MB: [3072][1024] bf16
  short* qkv = (short*)(ws + 14680064);  // 24 MB: [4096][3072] bf16 (V unused)
  short* Vt  = (short*)(ws + 39845888);  //  8 MB: [32][64][2048] bf16

  prep_kernel<<<dim3(4096 + 3072), dim3(256), 0, stream>>>(x, Wq, Wk, Wv, xb,
                                                           Wt);
  qkv_gemm_kernel<<<dim3(MTOT / 128, ND3 / 128), dim3(256), 0, stream>>>(
      xb, Wt, bq, bk, bv, qkv, Vt);
  attn_kernel<<<dim3(B_ * H_, S_ / 64), dim3(256), 0, stream>>>(qkv, Vt, out);
}

// Round 14
// 84.718 us; speedup vs baseline: 1.0375x; 1.0375x over previous
//
#include <hip/hip_runtime.h>
#include <hip/hip_bf16.h>
#include <stdint.h>

// Problem constants
#define B_    2
#define S_    2048
#define H_    16
#define DH_   64
#define D_    1024
#define ND3   3072      // 3*D
#define MTOT  4096      // B*S
#define L2E   1.4426950408889634f
#define MASKVAL (-3.0e38f)   // causal mask: exp2(MASKVAL) == 0
#define SBIAS   (-14.0f)     // static softmax offset (log2 units)

typedef __attribute__((ext_vector_type(8))) short bf16x8;
typedef __attribute__((ext_vector_type(4))) short bf16x4;
typedef __attribute__((ext_vector_type(4))) float f32x4;

__device__ inline short f2bs(float f) {
  __hip_bfloat16 h = __float2bfloat16(f);
  return *reinterpret_cast<short*>(&h);
}

__device__ inline void gl_lds16(const void* g, void* l) {
  __builtin_amdgcn_global_load_lds(
      (const __attribute__((address_space(1))) uint32_t*)g,
      (__attribute__((address_space(3))) uint32_t*)l, 16, 0, 0);
}

// --------------------------------------- fused prep: x->bf16 and W->Wt bf16
__global__ __launch_bounds__(256) void prep_kernel(
    const float* __restrict__ X, const float* __restrict__ Wq,
    const float* __restrict__ Wk, const float* __restrict__ Wv,
    short* __restrict__ Xb, short* __restrict__ Wt) {
  __shared__ float t[32][33];
  int bid = blockIdx.x;
  if (bid < 4096) {
    const int i = (bid * 256 + threadIdx.x) * 4;
    float4 v = *reinterpret_cast<const float4*>(X + i);
    bf16x4 o;
    o[0] = f2bs(v.x); o[1] = f2bs(v.y); o[2] = f2bs(v.z); o[3] = f2bs(v.w);
    *reinterpret_cast<bf16x4*>(Xb + i) = o;
  } else {
    bid -= 4096;
    const int z = bid >> 10;             // 0..2 : Wq/Wk/Wv
    const int rem = bid & 1023;
    const int n0 = (rem & 31) * 32, k0 = (rem >> 5) * 32;
    const int x = threadIdx.x & 31, y = threadIdx.x >> 5;   // y in 0..7
    const float* W = z == 0 ? Wq : (z == 1 ? Wk : Wv);
    short* out = Wt + (size_t)z * (D_ * D_);
#pragma unroll
    for (int i = 0; i < 4; ++i)
      t[y + 8 * i][x] = W[(size_t)(k0 + y + 8 * i) * D_ + n0 + x];
    __syncthreads();
#pragma unroll
    for (int i = 0; i < 4; ++i)
      out[(size_t)(n0 + y + 8 * i) * D_ + k0 + x] = f2bs(t[x][y + 8 * i]);
  }
}

// ------------------------------------------------- QKV GEMM, 256x256 8-phase
// 512 threads (8 waves: wm = wid>>2 in {0,1}, wn = wid&3). BK=64, 16 K-tiles.
// LDS 128KB: A halves (rows 0-127 / 128-255) and B halves, double-buffered.
// Per K-tile: 4 phases, each {stage-issue, ds_read frags, mid-barrier,
// 16 MFMA with setprio, end-barrier}; stages for tile j+1 issued at P0/P1
// into the free buffer; ONE vmcnt(0) drain per K-tile at P3-end (loads get
// 2-3 phases of compute to land, vs zero in the 2-barrier structure).
// Q/K tiles (bn<8) -> qkv rows (Q pre-scaled 0.125*L2E); V tiles (bn>=8)
// -> Vt[bh][dh][s] directly (fused transpose).
__global__ __launch_bounds__(512, 2) void qkv_gemm_kernel(
    const short* __restrict__ Xb, const short* __restrict__ Wt,
    const float* __restrict__ bq, const float* __restrict__ bk,
    const float* __restrict__ bv, short* __restrict__ QKV,
    short* __restrict__ Vt) {
  __shared__ char Lds[131072];
  const int tid = threadIdx.x;
  const int lane = tid & 63;
  const int wid = tid >> 6;
  const int l15 = lane & 15, lg = lane >> 4;
  const int wm = wid >> 2, wn = wid & 3;
  // XCD-aware swizzle: 192 blocks, 8 XCDs, 24 contiguous ids each (192%8==0).
  const int bid = blockIdx.x;
  const int wgid = (bid & 7) * 24 + (bid >> 3);
  const int m0 = (wgid / 12) * 256, n0 = (wgid % 12) * 256;

  // staging geometry (per half: 128 rows x 64 cols bf16 = 1024 16B chunks;
  // thread t stages chunks t and t+512; source col XOR-swizzled by row).
  const int srow = tid >> 3;                         // 0..63 (+64 for 2nd)
  const int scol = ((tid & 7) ^ (srow & 7)) * 8;
  const short* pa = Xb + (size_t)(m0 + srow) * D_ + scol;
  const short* pb = Wt + (size_t)(n0 + srow) * D_ + scol;
  char* sdst = Lds + (tid & 448) * 16;               // wave-uniform chunk base

  // fragment LDS byte offsets (within a region), swizzled reads
  const int abase = wm * 16384;                      // A region for this wave
  const int bbase = 65536 + (wn >> 1) * 16384;       // B region for this wave
  int a_off[8][2], b_off[4][2];
#pragma unroll
  for (int mr = 0; mr < 8; ++mr)
#pragma unroll
    for (int ks = 0; ks < 2; ++ks)
      a_off[mr][ks] =
          (mr * 16 + l15) * 128 + ((((ks * 4 + lg)) ^ (l15 & 7)) << 4);
#pragma unroll
  for (int nr = 0; nr < 4; ++nr)
#pragma unroll
    for (int ks = 0; ks < 2; ++ks)
      b_off[nr][ks] = ((wn & 1) * 64 + nr * 16 + l15) * 128 +
                      ((((ks * 4 + lg)) ^ (l15 & 7)) << 4);

  f32x4 acc[8][4];
#pragma unroll
  for (int i = 0; i < 8; ++i)
#pragma unroll
    for (int j = 0; j < 4; ++j) acc[i][j] = (f32x4){0.f, 0.f, 0.f, 0.f};

#define STG(P, RGN, KT, ROFF)                                                 \
  {                                                                           \
    const short* s_ = (P) + (size_t)(ROFF) * D_ + (KT) * 64;                  \
    gl_lds16(s_, sdst + (RGN));                                               \
    gl_lds16(s_ + (size_t)64 * D_, sdst + (RGN) + 8192);                      \
  }
#define BARRIER()                                                             \
  __builtin_amdgcn_s_barrier();                                               \
  __builtin_amdgcn_sched_barrier(0)

  // prologue: stage K-tile 0 (all four halves), drain, barrier
  STG(pa, 0, 0, 0);          // A half0 -> buf0
  STG(pa, 16384, 0, 128);    // A half1
  STG(pb, 65536, 0, 0);      // B half0
  STG(pb, 81920, 0, 128);    // B half1
  asm volatile("s_waitcnt vmcnt(0)" ::: "memory");
  BARRIER();

// one K-tile (4 phases), D_LIT = buffer parity (compile-time 0/1)
#define TILE(J, D_LIT)                                                        \
  {                                                                           \
    const int j_ = (J);                                                       \
    const bool stg = (j_ + 1 < 16);                                           \
    const int RD = (D_LIT) * 32768;          /* read buf byte offset   */     \
    const int WD = (1 - (D_LIT)) * 32768;    /* write (stage) buf      */     \
    bf16x8 af[8];                                                             \
    bf16x8 bfr0, bfr1;                                                        \
    /* ---- P0: stage A(j+1) both halves; frags ks0 nr{0,1} ---- */           \
    if (stg) {                                                                \
      STG(pa, WD + 0, j_ + 1, 0);                                             \
      STG(pa, WD + 16384, j_ + 1, 128);                                       \
    }                                                                         \
    _Pragma("unroll") for (int mr = 0; mr < 8; ++mr) af[mr] =                 \
        *reinterpret_cast<const bf16x8*>(Lds + RD + abase + a_off[mr][0]);    \
    bfr0 = *reinterpret_cast<const bf16x8*>(Lds + RD + bbase + b_off[0][0]);  \
    bfr1 = *reinterpret_cast<const bf16x8*>(Lds + RD + bbase + b_off[1][0]);  \
    BARRIER();                                                                \
    __builtin_amdgcn_s_setprio(1);                                            \
    _Pragma("unroll") for (int mr = 0; mr < 8; ++mr) {                        \
      acc[mr][0] = __builtin_amdgcn_mfma_f32_16x16x32_bf16(af[mr], bfr0,      \
                                                           acc[mr][0], 0, 0,  \
                                                           0);                \
      acc[mr][1] = __builtin_amdgcn_mfma_f32_16x16x32_bf16(af[mr], bfr1,      \
                                                           acc[mr][1], 0, 0,  \
                                                           0);                \
    }                                                                         \
    __builtin_amdgcn_s_setprio(0);                                            \
    BARRIER();                                                                \
    /* ---- P1: stage B(j+1) both halves; frags ks0 nr{2,3} ---- */           \
    if (stg) {                                                                \
      STG(pb, WD + 65536, j_ + 1, 0);                                         \
      STG(pb, WD + 81920, j_ + 1, 128);                                       \
    }                                                                         \
    bfr0 = *reinterpret_cast<const bf16x8*>(Lds + RD + bbase + b_off[2][0]);  \
    bfr1 = *reinterpret_cast<const bf16x8*>(Lds + RD + bbase + b_off[3][0]);  \
    BARRIER();                                                                \
    __builtin_amdgcn_s_setprio(1);                                            \
    _Pragma("unroll") for (int mr = 0; mr < 8; ++mr) {                        \
      acc[mr][2] = __builtin_amdgcn_mfma_f32_16x16x32_bf16(af[mr], bfr0,      \
                                                           acc[mr][2], 0, 0,  \
                                                           0);                \
      acc[mr][3] = __builtin_amdgcn_mfma_f32_16x16x32_bf16(af[mr], bfr1,      \
                                                           acc[mr][3], 0, 0,  \
                                                           0);                \
    }                                                                         \
    __builtin_amdgcn_s_setprio(0);                                            \
    BARRIER();                                                                \
    /* ---- P2: frags ks1 nr{0,1} ---- */                                     \
    _Pragma("unroll") for (int mr = 0; mr < 8; ++mr) af[mr] =                 \
        *reinterpret_cast<const bf16x8*>(Lds + RD + abase + a_off[mr][1]);    \
    bfr0 = *reinterpret_cast<const bf16x8*>(Lds + RD + bbase + b_off[0][1]);  \
    bfr1 = *reinterpret_cast<const bf16x8*>(Lds + RD + bbase + b_off[1][1]);  \
    BARRIER();                                                                \
    __builtin_amdgcn_s_setprio(1);                                            \
    _Pragma("unroll") for (int mr = 0; mr < 8; ++mr) {                        \
      acc[mr][0] = __builtin_amdgcn_mfma_f32_16x16x32_bf16(af[mr], bfr0,      \
                                                           acc[mr][0], 0, 0,  \
                                                           0);                \
      acc[mr][1] = __builtin_amdgcn_mfma_f32_16x16x32_bf16(af[mr], bfr1,      \
                                                           acc[mr][1], 0, 0,  \
                                                           0);                \
    }                                                                         \
    __builtin_amdgcn_s_setprio(0);                                            \
    BARRIER();                                                                \
    /* ---- P3: frags ks1 nr{2,3}; drain staged loads ---- */                 \
    bfr0 = *reinterpret_cast<const bf16x8*>(Lds + RD + bbase + b_off[2][1]);  \
    bfr1 = *reinterpret_cast<const bf16x8*>(Lds + RD + bbase + b_off[3][1]);  \
    BARRIER();                                                                \
    __builtin_amdgcn_s_setprio(1);                                            \
    _Pragma("unroll") for (int mr = 0; mr < 8; ++mr) {                        \
      acc[mr][2] = __builtin_amdgcn_mfma_f32_16x16x32_bf16(af[mr], bfr0,      \
                                                           acc[mr][2], 0, 0,  \
                                                           0);                \
      acc[mr][3] = __builtin_amdgcn_mfma_f32_16x16x32_bf16(af[mr], bfr1,      \
                                                           acc[mr][3], 0, 0,  \
                                                           0);                \
    }                                                                         \
    __builtin_amdgcn_s_setprio(0);                                            \
    asm volatile("s_waitcnt vmcnt(0)" ::: "memory");                          \
    BARRIER();                                                                \
  }

  for (int jj = 0; jj < 16; jj += 2) {
    TILE(jj, 0);
    TILE(jj + 1, 1);
  }
#undef TILE
#undef STG
#undef BARRIER

  // ---- epilogue ----
  const int wr = wm * 128, wc = wn * 64;
  if (n0 < 2 * D_) {  // Q or K tiles (bn 0..7; tiles never mix Q/K: 256|1024)
#pragma unroll
    for (int nr = 0; nr < 4; ++nr) {
      const int col = n0 + wc + nr * 16 + l15;
      float bias, qs;
      if (col < D_) { bias = bq[col];      qs = 0.125f * L2E; }
      else          { bias = bk[col - D_]; qs = 1.f; }
#pragma unroll
      for (int mr = 0; mr < 8; ++mr)
#pragma unroll
        for (int r = 0; r < 4; ++r) {
          const int row = m0 + wr + mr * 16 + lg * 4 + r;
          QKV[(size_t)row * ND3 + col] = f2bs((acc[mr][nr][r] + bias) * qs);
        }
    }
  } else {  // V tiles -> Vt[bh][dh][s] directly (fused transpose)
    const int bb = m0 >> 11;
    const int srow_base = (m0 & 2047) + wr + lg * 4;
#pragma unroll
    for (int nr = 0; nr < 4; ++nr) {
      const int f = n0 + wc + nr * 16 + l15 - 2 * D_;  // v-feature 0..1023
      const float bias = bv[f];
      short* vout = Vt + ((size_t)(bb * H_ + (f >> 6)) * DH_ + (f & 63)) * S_;
#pragma unroll
      for (int mr = 0; mr < 8; ++mr) {
        bf16x4 pv;
#pragma unroll
        for (int r = 0; r < 4; ++r) pv[r] = f2bs(acc[mr][nr][r] + bias);
        *reinterpret_cast<bf16x4*>(vout + srow_base + mr * 16) = pv;
      }
    }
  }
}

// ----------------------------------------------------------- flash attention
// r12 attn verbatim (best measured: 43.0 us): static-offset softmax (SBIAS
// folded into QK C-init), 2 K-slots + 3 V-slots (40KB), 4 blocks/CU, QK one
// tile ahead, raw barrier + vmcnt drain, XOR-swizzled staging, LPT order.
__global__ __launch_bounds__(256, 4) void attn_kernel(
    const short* __restrict__ QKV, const short* __restrict__ Vtg,
    float* __restrict__ Out) {
  __shared__ short KV[5][4096];   // 40KB: K slots @0,8192; V @16384/24576/32768
  const int tid = threadIdx.x;
  const int lane = tid & 63, wid = tid >> 6;
  const int l15 = lane & 15, lg = lane >> 4;
  const int bh = blockIdx.x;
  const int qt = (S_ / 64 - 1) - (int)blockIdx.y;   // LPT: longest first
  const int b = bh >> 4, h = bh & 15;
  const int q0 = qt * 64;
  const short* Qg = QKV + (size_t)b * S_ * ND3 + h * DH_;
  const short* Kg = QKV + (size_t)b * S_ * ND3 + D_ + h * DH_;
  const short* Vg = Vtg + (size_t)bh * DH_ * S_;

  const int srow = tid >> 3;
  const int scol = ((tid & 7) ^ (srow & 7)) * 8;
  const char* kbase = (const char*)&KV[0][0];
  char* dst = (char*)kbase + (tid & 192) * 16;
  int ka[2];
#pragma unroll
  for (int ks = 0; ks < 2; ++ks)
    ka[ks] = l15 * 128 + ((((ks * 4 + lg)) ^ (l15 & 7)) << 4);
  int va[4];
#pragma unroll
  for (int ntk = 0; ntk < 4; ++ntk)
    va[ntk] = l15 * 128 + (((2 * ntk + (lg >> 1)) ^ (l15 & 7)) << 4) +
              ((lg & 1) << 3);
  const int qrow_g = q0 + wid * 16 + l15;

  bf16x8 qf[2];
#pragma unroll
  for (int ks = 0; ks < 2; ++ks)
    qf[ks] = *reinterpret_cast<const bf16x8*>(Qg + (size_t)qrow_g * ND3 +
                                              ks * 32 + lg * 8);

  f32x4 o[4];
#pragma unroll
  for (int i = 0; i < 4; ++i) o[i] = (f32x4){0.f, 0.f, 0.f, 0.f};
  float lsum = 0.f;

  const short* kp = Kg + (size_t)srow * ND3 + scol;
  const short* vp = Vg + (size_t)srow * S_ + scol;

#define STAGE_AT(KOFF, VOFF)                                                  \
  {                                                                           \
    gl_lds16(kp, dst + (KOFF));                                               \
    gl_lds16(kp + 32 * ND3, dst + (KOFF) + 4096);                             \
    gl_lds16(vp, dst + (VOFF));                                               \
    gl_lds16(vp + 32 * S_, dst + (VOFF) + 4096);                              \
    kp += 64 * ND3;                                                           \
    vp += 64;                                                                 \
  }

  int kr = 8192, kw = 0;
  int vr = 16384, vw = 32768;          // VSUM = 73728

  STAGE_AT(0, 16384);
  if (qt >= 1) STAGE_AT(8192, 24576);
  asm volatile("s_waitcnt vmcnt(0)" ::: "memory");
  __builtin_amdgcn_s_barrier();
  __builtin_amdgcn_sched_barrier(0);

  f32x4 sA[4], sB[4];
#pragma unroll
  for (int i = 0; i < 4; ++i) sA[i] = (f32x4){SBIAS, SBIAS, SBIAS, SBIAS};
#pragma unroll
  for (int ks = 0; ks < 2; ++ks)
#pragma unroll
    for (int nt = 0; nt < 4; ++nt) {
      const bf16x8 kf =
          *reinterpret_cast<const bf16x8*>(kbase + ka[ks] + nt * 2048);
      sA[nt] = __builtin_amdgcn_mfma_f32_16x16x32_bf16(kf, qf[ks], sA[nt],
                                                       0, 0, 0);
    }

#define STEP_BODY(T, SC, SN)                                                  \
  {                                                                           \
    const int T_ = (T);                                                       \
    if (T_ + 2 <= qt) STAGE_AT(kw, vw);                                       \
    if (T_ + 1 <= qt) {                                                       \
      _Pragma("unroll") for (int i = 0; i < 4; ++i)                           \
          SN[i] = (f32x4){SBIAS, SBIAS, SBIAS, SBIAS};                        \
      _Pragma("unroll") for (int ks = 0; ks < 2; ++ks)                        \
        _Pragma("unroll") for (int nt = 0; nt < 4; ++nt) {                    \
          const bf16x8 kf = *reinterpret_cast<const bf16x8*>(                 \
              kbase + kr + ka[ks] + nt * 2048);                               \
          SN[nt] = __builtin_amdgcn_mfma_f32_16x16x32_bf16(kf, qf[ks],        \
                                                           SN[nt], 0, 0, 0);  \
        }                                                                     \
    }                                                                         \
    if (T_ == qt) { /* causal mask on diagonal tile */                        \
      const int kv0 = T_ * 64;                                                \
      _Pragma("unroll") for (int nt = 0; nt < 4; ++nt)                        \
        _Pragma("unroll") for (int r = 0; r < 4; ++r)                         \
          if (kv0 + nt * 16 + lg * 4 + r > qrow_g) SC[nt][r] = MASKVAL;       \
    }                                                                         \
    float rowsum = 0.f;                                                       \
    bf16x4 pk[4];                                                             \
    _Pragma("unroll") for (int nt = 0; nt < 4; ++nt) {                        \
      const float p0 = exp2f(SC[nt][0]);                                      \
      const float p1 = exp2f(SC[nt][1]);                                      \
      const float p2 = exp2f(SC[nt][2]);                                      \
      const float p3 = exp2f(SC[nt][3]);                                      \
      rowsum += (p0 + p1) + (p2 + p3);                                        \
      union { uint32_t u[2]; bf16x4 v; } pu;                                  \
      pu.u[0] = (__float_as_uint(p1) & 0xffff0000u) |                         \
                (__float_as_uint(p0) >> 16);                                  \
      pu.u[1] = (__float_as_uint(p3) & 0xffff0000u) |                         \
                (__float_as_uint(p2) >> 16);                                  \
      pk[nt] = pu.v;                                                          \
    }                                                                         \
    lsum += rowsum;                                                           \
    _Pragma("unroll") for (int ntk = 0; ntk < 4; ++ntk)                       \
      _Pragma("unroll") for (int ntd = 0; ntd < 4; ++ntd) {                   \
        const bf16x4 vf = *reinterpret_cast<const bf16x4*>(                   \
            kbase + vr + va[ntk] + ntd * 2048);                               \
        o[ntd] = __builtin_amdgcn_mfma_f32_16x16x16bf16_1k(vf, pk[ntk],       \
                                                           o[ntd], 0, 0, 0);  \
      }                                                                       \
    if (T_ < qt) {                                                            \
      asm volatile("s_waitcnt vmcnt(0)" ::: "memory");                        \
      __builtin_amdgcn_s_barrier();                                           \
      __builtin_amdgcn_sched_barrier(0);                                      \
    }                                                                         \
    kr ^= 8192; kw ^= 8192;                                                   \
    { const int tv = vr; vr = 73728 - vr - vw; vw = tv; }                     \
  }

  for (int t = 0; t <= qt; t += 2) {
    STEP_BODY(t, sA, sB);
    if (t + 1 <= qt) STEP_BODY(t + 1, sB, sA);
  }
#undef STEP_BODY
#undef STAGE_AT

  float ls = lsum;
  ls += __shfl_xor(ls, 16);
  ls += __shfl_xor(ls, 32);
  const float inv = 1.f / ls;
#pragma unroll
  for (int nt = 0; nt < 4; ++nt) {
    f32x4 v = {o[nt][0] * inv, o[nt][1] * inv, o[nt][2] * inv, o[nt][3] * inv};
    *reinterpret_cast<f32x4*>(
        &Out[((size_t)b * S_ + qrow_g) * D_ + h * DH_ + nt * 16 + lg * 4]) = v;
  }
}

// ---------------------------------------------------------------- launcher
extern "C" void kernel_launch(void* const* d_in, const int* in_sizes, int n_in,
                              void* d_out, int out_size, void* d_ws,
                              size_t ws_size, hipStream_t stream) {
  const float* x  = (const float*)d_in[0];
  const float* Wq = (const float*)d_in[1];
  const float* bq = (const float*)d_in[2];
  const float* Wk = (const float*)d_in[3];
  const float* bk = (const float*)d_in[4];
  const float* Wv = (const float*)d_in[5];
  const float* bv = (const float*)d_in[6];
  float* out = (float*)d_out;

  char* ws = (char*)d_ws;
  short* xb  = (short*)(ws);             //  8 MB: [4096][1024] bf16
  short* Wt  = (short*)(ws + 8388608);   //  6 MB: [3072][1024] bf16
  short* qkv = (short*)(ws + 14680064);  // 24 MB: [4096][3072] bf16 (V unused)
  short* Vt  = (short*)(ws + 39845888);  //  8 MB: [32][64][2048] bf16

  prep_kernel<<<dim3(4096 + 3072), dim3(256), 0, stream>>>(x, Wq, Wk, Wv, xb,
                                                           Wt);
  qkv_gemm_kernel<<<dim3(192), dim3(512), 0, stream>>>(xb, Wt, bq, bk, bv,
                                                       qkv, Vt);
  attn_kernel<<<dim3(B_ * H_, S_ / 64), dim3(256), 0, stream>>>(qkv, Vt, out);
}

// Round 15
// 79.421 us; speedup vs baseline: 1.1067x; 1.0667x over previous
//
#include <hip/hip_runtime.h>
#include <hip/hip_bf16.h>
#include <stdint.h>

// Problem constants
#define B_    2
#define S_    2048
#define H_    16
#define DH_   64
#define D_    1024
#define ND3   3072      // 3*D
#define MTOT  4096      // B*S
#define L2E   1.4426950408889634f
#define MASKVAL (-3.0e38f)   // causal mask: exp2(MASKVAL) == 0
#define SBIAS   (-14.0f)     // static softmax offset (log2 units)

typedef __attribute__((ext_vector_type(8))) short bf16x8;
typedef __attribute__((ext_vector_type(4))) short bf16x4;
typedef __attribute__((ext_vector_type(4))) float f32x4;

__device__ inline short f2bs(float f) {
  __hip_bfloat16 h = __float2bfloat16(f);
  return *reinterpret_cast<short*>(&h);
}

__device__ inline void gl_lds16(const void* g, void* l) {
  __builtin_amdgcn_global_load_lds(
      (const __attribute__((address_space(1))) uint32_t*)g,
      (__attribute__((address_space(3))) uint32_t*)l, 16, 0, 0);
}

// --------------------------------------- fused prep: x->bf16 and W->Wt bf16
__global__ __launch_bounds__(256) void prep_kernel(
    const float* __restrict__ X, const float* __restrict__ Wq,
    const float* __restrict__ Wk, const float* __restrict__ Wv,
    short* __restrict__ Xb, short* __restrict__ Wt) {
  __shared__ float t[32][33];
  int bid = blockIdx.x;
  if (bid < 4096) {
    const int i = (bid * 256 + threadIdx.x) * 4;
    float4 v = *reinterpret_cast<const float4*>(X + i);
    bf16x4 o;
    o[0] = f2bs(v.x); o[1] = f2bs(v.y); o[2] = f2bs(v.z); o[3] = f2bs(v.w);
    *reinterpret_cast<bf16x4*>(Xb + i) = o;
  } else {
    bid -= 4096;
    const int z = bid >> 10;             // 0..2 : Wq/Wk/Wv
    const int rem = bid & 1023;
    const int n0 = (rem & 31) * 32, k0 = (rem >> 5) * 32;
    const int x = threadIdx.x & 31, y = threadIdx.x >> 5;   // y in 0..7
    const float* W = z == 0 ? Wq : (z == 1 ? Wk : Wv);
    short* out = Wt + (size_t)z * (D_ * D_);
#pragma unroll
    for (int i = 0; i < 4; ++i)
      t[y + 8 * i][x] = W[(size_t)(k0 + y + 8 * i) * D_ + n0 + x];
    __syncthreads();
#pragma unroll
    for (int i = 0; i < 4; ++i)
      out[(size_t)(n0 + y + 8 * i) * D_ + k0 + x] = f2bs(t[x][y + 8 * i]);
  }
}

// ------------------------------------------------- QKV GEMM, 256x192 8-phase
// Grid = 16 x 16 = 256 blocks = EXACTLY 1/CU (r14's 192-block grid left 25%
// of the machine idle). 512 threads (8 waves: wm=wid>>2, wn=wid&3), BK=64,
// 16 K-tiles, LDS 112KB double-buffered (A 32KB + B 24KB per buffer).
// Per K-tile 4 phases: {stage-issue, ds_read frags, barrier, 12 MFMA with
// setprio, barrier}; stages for tile j+1 at P0(A-lo)/P1(A-hi)/P2(B); single
// vmcnt(0) drain at P3-end (loads get 1-3 phases of compute to land).
// Epilogue per-nr col branch (boundaries 1024/2048 are x16 -> wave-uniform):
// Q cols scaled 0.125*L2E -> qkv; K -> qkv; V -> Vt[bh][dh][s] transposed.
__global__ __launch_bounds__(512, 2) void qkv_gemm_kernel(
    const short* __restrict__ Xb, const short* __restrict__ Wt,
    const float* __restrict__ bq, const float* __restrict__ bk,
    const float* __restrict__ bv, short* __restrict__ QKV,
    short* __restrict__ Vt) {
  __shared__ char Lds[114688];   // buf d: A @ d*57344 (32KB), B @ +32768 (24KB)
  const int tid = threadIdx.x;
  const int lane = tid & 63;
  const int wid = tid >> 6;
  const int l15 = lane & 15, lg = lane >> 4;
  const int wm = wid >> 2, wn = wid & 3;
  // XCD-aware bijective swizzle (256 % 8 == 0)
  const int bid = blockIdx.x;
  const int wgid = (bid & 7) * 32 + (bid >> 3);
  const int m0 = (wgid >> 4) * 256, n0 = (wgid & 15) * 192;

  // staging: each 8KB piece = 64 rows x 128B; thread t writes chunk t
  // (lds byte t*16) from source row srow, col XOR-swizzled by row&7.
  const int srow = tid >> 3;                         // 0..63
  const int scol = ((tid & 7) ^ (srow & 7)) * 8;
  const short* pa = Xb + (size_t)(m0 + srow) * D_ + scol;
  const short* pb = Wt + (size_t)(n0 + srow) * D_ + scol;
  char* sdst = Lds + (tid & 448) * 16;               // wave-uniform base

  const int abase = wm * 16384;                      // A rows wm*128..+127
  int a_off[8][2], b_off[3][2];
#pragma unroll
  for (int mr = 0; mr < 8; ++mr)
#pragma unroll
    for (int ks = 0; ks < 2; ++ks)
      a_off[mr][ks] =
          (mr * 16 + l15) * 128 + ((((ks * 4 + lg)) ^ (l15 & 7)) << 4);
#pragma unroll
  for (int nr = 0; nr < 3; ++nr)
#pragma unroll
    for (int ks = 0; ks < 2; ++ks)
      b_off[nr][ks] = (wn * 48 + nr * 16 + l15) * 128 +
                      ((((ks * 4 + lg)) ^ (l15 & 7)) << 4);

  f32x4 acc[8][3];
#pragma unroll
  for (int i = 0; i < 8; ++i)
#pragma unroll
    for (int j = 0; j < 3; ++j) acc[i][j] = (f32x4){0.f, 0.f, 0.f, 0.f};

#define BARRIER()                                                             \
  __builtin_amdgcn_s_barrier();                                               \
  __builtin_amdgcn_sched_barrier(0)

  // prologue: stage tile 0 fully into buf0 (4 A pieces + 3 B pieces)
  gl_lds16(pa, sdst);
  gl_lds16(pa + (size_t)64 * D_, sdst + 8192);
  gl_lds16(pa + (size_t)128 * D_, sdst + 16384);
  gl_lds16(pa + (size_t)192 * D_, sdst + 24576);
  gl_lds16(pb, sdst + 32768);
  gl_lds16(pb + (size_t)64 * D_, sdst + 40960);
  gl_lds16(pb + (size_t)128 * D_, sdst + 49152);
  asm volatile("s_waitcnt vmcnt(0)" ::: "memory");
  BARRIER();

// one K-tile (4 phases), DL = buffer parity (compile-time 0/1)
#define TILE(J, DL)                                                           \
  {                                                                           \
    const int j_ = (J);                                                       \
    const bool stg = (j_ + 1 < 16);                                           \
    const int RD = (DL) * 57344;                                              \
    const int WD = (1 - (DL)) * 57344;                                        \
    const short* pa1 = pa + (j_ + 1) * 64;                                    \
    const short* pb1 = pb + (j_ + 1) * 64;                                    \
    bf16x8 af[4], bf0, bf1, bf2;                                              \
    /* P0: stage A rows 0-127; frags B ks0 + A ks0 mr0-3; MFMA acc[0..3] */   \
    if (stg) {                                                                \
      gl_lds16(pa1, sdst + WD);                                               \
      gl_lds16(pa1 + (size_t)64 * D_, sdst + WD + 8192);                      \
    }                                                                         \
    bf0 = *reinterpret_cast<const bf16x8*>(Lds + RD + 32768 + b_off[0][0]);   \
    bf1 = *reinterpret_cast<const bf16x8*>(Lds + RD + 32768 + b_off[1][0]);   \
    bf2 = *reinterpret_cast<const bf16x8*>(Lds + RD + 32768 + b_off[2][0]);   \
    _Pragma("unroll") for (int mr = 0; mr < 4; ++mr) af[mr] =                 \
        *reinterpret_cast<const bf16x8*>(Lds + RD + abase + a_off[mr][0]);    \
    BARRIER();                                                                \
    __builtin_amdgcn_s_setprio(1);                                            \
    _Pragma("unroll") for (int mr = 0; mr < 4; ++mr) {                        \
      acc[mr][0] = __builtin_amdgcn_mfma_f32_16x16x32_bf16(af[mr], bf0,       \
                                                           acc[mr][0], 0, 0,  \
                                                           0);                \
      acc[mr][1] = __builtin_amdgcn_mfma_f32_16x16x32_bf16(af[mr], bf1,       \
                                                           acc[mr][1], 0, 0,  \
                                                           0);                \
      acc[mr][2] = __builtin_amdgcn_mfma_f32_16x16x32_bf16(af[mr], bf2,       \
                                                           acc[mr][2], 0, 0,  \
                                                           0);                \
    }                                                                         \
    __builtin_amdgcn_s_setprio(0);                                            \
    BARRIER();                                                                \
    /* P1: stage A rows 128-255; frags A ks0 mr4-7; MFMA acc[4..7] */         \
    if (stg) {                                                                \
      gl_lds16(pa1 + (size_t)128 * D_, sdst + WD + 16384);                    \
      gl_lds16(pa1 + (size_t)192 * D_, sdst + WD + 24576);                    \
    }                                                                         \
    _Pragma("unroll") for (int mr = 0; mr < 4; ++mr) af[mr] =                 \
        *reinterpret_cast<const bf16x8*>(Lds + RD + abase +                   \
                                         a_off[mr + 4][0]);                   \
    BARRIER();                                                                \
    __builtin_amdgcn_s_setprio(1);                                            \
    _Pragma("unroll") for (int mr = 0; mr < 4; ++mr) {                        \
      acc[mr + 4][0] = __builtin_amdgcn_mfma_f32_16x16x32_bf16(               \
          af[mr], bf0, acc[mr + 4][0], 0, 0, 0);                              \
      acc[mr + 4][1] = __builtin_amdgcn_mfma_f32_16x16x32_bf16(               \
          af[mr], bf1, acc[mr + 4][1], 0, 0, 0);                              \
      acc[mr + 4][2] = __builtin_amdgcn_mfma_f32_16x16x32_bf16(               \
          af[mr], bf2, acc[mr + 4][2], 0, 0, 0);                              \
    }                                                                         \
    __builtin_amdgcn_s_setprio(0);                                            \
    BARRIER();                                                                \
    /* P2: stage B rows 0-191; frags B ks1 + A ks1 mr0-3; MFMA acc[0..3] */   \
    if (stg) {                                                                \
      gl_lds16(pb1, sdst + WD + 32768);                                       \
      gl_lds16(pb1 + (size_t)64 * D_, sdst + WD + 40960);                     \
      gl_lds16(pb1 + (size_t)128 * D_, sdst + WD + 49152);                    \
    }                                                                         \
    bf0 = *reinterpret_cast<const bf16x8*>(Lds + RD + 32768 + b_off[0][1]);   \
    bf1 = *reinterpret_cast<const bf16x8*>(Lds + RD + 32768 + b_off[1][1]);   \
    bf2 = *reinterpret_cast<const bf16x8*>(Lds + RD + 32768 + b_off[2][1]);   \
    _Pragma("unroll") for (int mr = 0; mr < 4; ++mr) af[mr] =                 \
        *reinterpret_cast<const bf16x8*>(Lds + RD + abase + a_off[mr][1]);    \
    BARRIER();                                                                \
    __builtin_amdgcn_s_setprio(1);                                            \
    _Pragma("unroll") for (int mr = 0; mr < 4; ++mr) {                        \
      acc[mr][0] = __builtin_amdgcn_mfma_f32_16x16x32_bf16(af[mr], bf0,       \
                                                           acc[mr][0], 0, 0,  \
                                                           0);                \
      acc[mr][1] = __builtin_amdgcn_mfma_f32_16x16x32_bf16(af[mr], bf1,       \
                                                           acc[mr][1], 0, 0,  \
                                                           0);                \
      acc[mr][2] = __builtin_amdgcn_mfma_f32_16x16x32_bf16(af[mr], bf2,       \
                                                           acc[mr][2], 0, 0,  \
                                                           0);                \
    }                                                                         \
    __builtin_amdgcn_s_setprio(0);                                            \
    BARRIER();                                                                \
    /* P3: frags A ks1 mr4-7; MFMA acc[4..7]; drain staged loads */           \
    _Pragma("unroll") for (int mr = 0; mr < 4; ++mr) af[mr] =                 \
        *reinterpret_cast<const bf16x8*>(Lds + RD + abase +                   \
                                         a_off[mr + 4][1]);                   \
    BARRIER();                                                                \
    __builtin_amdgcn_s_setprio(1);                                            \
    _Pragma("unroll") for (int mr = 0; mr < 4; ++mr) {                        \
      acc[mr + 4][0] = __builtin_amdgcn_mfma_f32_16x16x32_bf16(               \
          af[mr], bf0, acc[mr + 4][0], 0, 0, 0);                              \
      acc[mr + 4][1] = __builtin_amdgcn_mfma_f32_16x16x32_bf16(               \
          af[mr], bf1, acc[mr + 4][1], 0, 0, 0);                              \
      acc[mr + 4][2] = __builtin_amdgcn_mfma_f32_16x16x32_bf16(               \
          af[mr], bf2, acc[mr + 4][2], 0, 0, 0);                              \
    }                                                                         \
    __builtin_amdgcn_s_setprio(0);                                            \
    asm volatile("s_waitcnt vmcnt(0)" ::: "memory");                          \
    BARRIER();                                                                \
  }

  for (int jj = 0; jj < 16; jj += 2) {
    TILE(jj, 0);
    TILE(jj + 1, 1);
  }
#undef TILE
#undef BARRIER

  // ---- epilogue (per-nr column branch; boundaries are multiples of 16) ----
  const int wr = wm * 128;
#pragma unroll
  for (int nr = 0; nr < 3; ++nr) {
    const int col = n0 + wn * 48 + nr * 16 + l15;
    if (col < 2 * D_) {  // Q or K -> qkv rows
      float bias, qs;
      if (col < D_) { bias = bq[col];      qs = 0.125f * L2E; }
      else          { bias = bk[col - D_]; qs = 1.f; }
#pragma unroll
      for (int mr = 0; mr < 8; ++mr)
#pragma unroll
        for (int r = 0; r < 4; ++r) {
          const int row = m0 + wr + mr * 16 + lg * 4 + r;
          QKV[(size_t)row * ND3 + col] = f2bs((acc[mr][nr][r] + bias) * qs);
        }
    } else {  // V -> Vt[bh][dh][s] directly (fused transpose)
      const int f = col - 2 * D_;                    // v-feature 0..1023
      const float bias = bv[f];
      const int bb = m0 >> 11;
      const int srow_base = (m0 & 2047) + wr + lg * 4;
      short* vout = Vt + ((size_t)(bb * H_ + (f >> 6)) * DH_ + (f & 63)) * S_;
#pragma unroll
      for (int mr = 0; mr < 8; ++mr) {
        bf16x4 pv;
#pragma unroll
        for (int r = 0; r < 4; ++r) pv[r] = f2bs(acc[mr][nr][r] + bias);
        *reinterpret_cast<bf16x4*>(vout + srow_base + mr * 16) = pv;
      }
    }
  }
}

// ----------------------------------------------------------- flash attention
// r12 attn verbatim (best measured: 43.0 us).
__global__ __launch_bounds__(256, 4) void attn_kernel(
    const short* __restrict__ QKV, const short* __restrict__ Vtg,
    float* __restrict__ Out) {
  __shared__ short KV[5][4096];   // 40KB: K slots @0,8192; V @16384/24576/32768
  const int tid = threadIdx.x;
  const int lane = tid & 63, wid = tid >> 6;
  const int l15 = lane & 15, lg = lane >> 4;
  const int bh = blockIdx.x;
  const int qt = (S_ / 64 - 1) - (int)blockIdx.y;   // LPT: longest first
  const int b = bh >> 4, h = bh & 15;
  const int q0 = qt * 64;
  const short* Qg = QKV + (size_t)b * S_ * ND3 + h * DH_;
  const short* Kg = QKV + (size_t)b * S_ * ND3 + D_ + h * DH_;
  const short* Vg = Vtg + (size_t)bh * DH_ * S_;

  const int srow = tid >> 3;
  const int scol = ((tid & 7) ^ (srow & 7)) * 8;
  const char* kbase = (const char*)&KV[0][0];
  char* dst = (char*)kbase + (tid & 192) * 16;
  int ka[2];
#pragma unroll
  for (int ks = 0; ks < 2; ++ks)
    ka[ks] = l15 * 128 + ((((ks * 4 + lg)) ^ (l15 & 7)) << 4);
  int va[4];
#pragma unroll
  for (int ntk = 0; ntk < 4; ++ntk)
    va[ntk] = l15 * 128 + (((2 * ntk + (lg >> 1)) ^ (l15 & 7)) << 4) +
              ((lg & 1) << 3);
  const int qrow_g = q0 + wid * 16 + l15;

  bf16x8 qf[2];
#pragma unroll
  for (int ks = 0; ks < 2; ++ks)
    qf[ks] = *reinterpret_cast<const bf16x8*>(Qg + (size_t)qrow_g * ND3 +
                                              ks * 32 + lg * 8);

  f32x4 o[4];
#pragma unroll
  for (int i = 0; i < 4; ++i) o[i] = (f32x4){0.f, 0.f, 0.f, 0.f};
  float lsum = 0.f;

  const short* kp = Kg + (size_t)srow * ND3 + scol;
  const short* vp = Vg + (size_t)srow * S_ + scol;

#define STAGE_AT(KOFF, VOFF)                                                  \
  {                                                                           \
    gl_lds16(kp, dst + (KOFF));                                               \
    gl_lds16(kp + 32 * ND3, dst + (KOFF) + 4096);                             \
    gl_lds16(vp, dst + (VOFF));                                               \
    gl_lds16(vp + 32 * S_, dst + (VOFF) + 4096);                              \
    kp += 64 * ND3;                                                           \
    vp += 64;                                                                 \
  }

  int kr = 8192, kw = 0;
  int vr = 16384, vw = 32768;          // VSUM = 73728

  STAGE_AT(0, 16384);
  if (qt >= 1) STAGE_AT(8192, 24576);
  asm volatile("s_waitcnt vmcnt(0)" ::: "memory");
  __builtin_amdgcn_s_barrier();
  __builtin_amdgcn_sched_barrier(0);

  f32x4 sA[4], sB[4];
#pragma unroll
  for (int i = 0; i < 4; ++i) sA[i] = (f32x4){SBIAS, SBIAS, SBIAS, SBIAS};
#pragma unroll
  for (int ks = 0; ks < 2; ++ks)
#pragma unroll
    for (int nt = 0; nt < 4; ++nt) {
      const bf16x8 kf =
          *reinterpret_cast<const bf16x8*>(kbase + ka[ks] + nt * 2048);
      sA[nt] = __builtin_amdgcn_mfma_f32_16x16x32_bf16(kf, qf[ks], sA[nt],
                                                       0, 0, 0);
    }

#define STEP_BODY(T, SC, SN)                                                  \
  {                                                                           \
    const int T_ = (T);                                                       \
    if (T_ + 2 <= qt) STAGE_AT(kw, vw);                                       \
    if (T_ + 1 <= qt) {                                                       \
      _Pragma("unroll") for (int i = 0; i < 4; ++i)                           \
          SN[i] = (f32x4){SBIAS, SBIAS, SBIAS, SBIAS};                        \
      _Pragma("unroll") for (int ks = 0; ks < 2; ++ks)                        \
        _Pragma("unroll") for (int nt = 0; nt < 4; ++nt) {                    \
          const bf16x8 kf = *reinterpret_cast<const bf16x8*>(                 \
              kbase + kr + ka[ks] + nt * 2048);                               \
          SN[nt] = __builtin_amdgcn_mfma_f32_16x16x32_bf16(kf, qf[ks],        \
                                                           SN[nt], 0, 0, 0);  \
        }                                                                     \
    }                                                                         \
    if (T_ == qt) { /* causal mask on diagonal tile */                        \
      const int kv0 = T_ * 64;                                                \
      _Pragma("unroll") for (int nt = 0; nt < 4; ++nt)                        \
        _Pragma("unroll") for (int r = 0; r < 4; ++r)                         \
          if (kv0 + nt * 16 + lg * 4 + r > qrow_g) SC[nt][r] = MASKVAL;       \
    }                                                                         \
    float rowsum = 0.f;                                                       \
    bf16x4 pk[4];                                                             \
    _Pragma("unroll") for (int nt = 0; nt < 4; ++nt) {                        \
      const float p0 = exp2f(SC[nt][0]);                                      \
      const float p1 = exp2f(SC[nt][1]);                                      \
      const float p2 = exp2f(SC[nt][2]);                                      \
      const float p3 = exp2f(SC[nt][3]);                                      \
      rowsum += (p0 + p1) + (p2 + p3);                                        \
      union { uint32_t u[2]; bf16x4 v; } pu;                                  \
      pu.u[0] = (__float_as_uint(p1) & 0xffff0000u) |                         \
                (__float_as_uint(p0) >> 16);                                  \
      pu.u[1] = (__float_as_uint(p3) & 0xffff0000u) |                         \
                (__float_as_uint(p2) >> 16);                                  \
      pk[nt] = pu.v;                                                          \
    }                                                                         \
    lsum += rowsum;                                                           \
    _Pragma("unroll") for (int ntk = 0; ntk < 4; ++ntk)                       \
      _Pragma("unroll") for (int ntd = 0; ntd < 4; ++ntd) {                   \
        const bf16x4 vf = *reinterpret_cast<const bf16x4*>(                   \
            kbase + vr + va[ntk] + ntd * 2048);                               \
        o[ntd] = __builtin_amdgcn_mfma_f32_16x16x16bf16_1k(vf, pk[ntk],       \
                                                           o[ntd], 0, 0, 0);  \
      }                                                                       \
    if (T_ < qt) {                                                            \
      asm volatile("s_waitcnt vmcnt(0)" ::: "memory");                        \
      __builtin_amdgcn_s_barrier();                                           \
      __builtin_amdgcn_sched_barrier(0);                                      \
    }                                                                         \
    kr ^= 8192; kw ^= 8192;                                                   \
    { const int tv = vr; vr = 73728 - vr - vw; vw = tv; }                     \
  }

  for (int t = 0; t <= qt; t += 2) {
    STEP_BODY(t, sA, sB);
    if (t + 1 <= qt) STEP_BODY(t + 1, sB, sA);
  }
#undef STEP_BODY
#undef STAGE_AT

  float ls = lsum;
  ls += __shfl_xor(ls, 16);
  ls += __shfl_xor(ls, 32);
  const float inv = 1.f / ls;
#pragma unroll
  for (int nt = 0; nt < 4; ++nt) {
    f32x4 v = {o[nt][0] * inv, o[nt][1] * inv, o[nt][2] * inv, o[nt][3] * inv};
    *reinterpret_cast<f32x4*>(
        &Out[((size_t)b * S_ + qrow_g) * D_ + h * DH_ + nt * 16 + lg * 4]) = v;
  }
}

// ---------------------------------------------------------------- launcher
extern "C" void kernel_launch(void* const* d_in, const int* in_sizes, int n_in,
                              void* d_out, int out_size, void* d_ws,
                              size_t ws_size, hipStream_t stream) {
  const float* x  = (const float*)d_in[0];
  const float* Wq = (const float*)d_in[1];
  const float* bq = (const float*)d_in[2];
  const float* Wk = (const float*)d_in[3];
  const float* bk = (const float*)d_in[4];
  const float* Wv = (const float*)d_in[5];
  const float* bv = (const float*)d_in[6];
  float* out = (float*)d_out;

  char* ws = (char*)d_ws;
  short* xb  = (short*)(ws);             //  8 MB: [4096][1024] bf16
  short* Wt  = (short*)(ws + 8388608);   //  6 MB: [3072][1024] bf16
  short* qkv = (short*)(ws + 14680064);  // 24 MB: [4096][3072] bf16 (V unused)
  short* Vt  = (short*)(ws + 39845888);  //  8 MB: [32][64][2048] bf16

  prep_kernel<<<dim3(4096 + 3072), dim3(256), 0, stream>>>(x, Wq, Wk, Wv, xb,
                                                           Wt);
  qkv_gemm_kernel<<<dim3(256), dim3(512), 0, stream>>>(xb, Wt, bq, bk, bv,
                                                       qkv, Vt);
  attn_kernel<<<dim3(B_ * H_, S_ / 64), dim3(256), 0, stream>>>(qkv, Vt, out);
}

// Round 16
// 77.008 us; speedup vs baseline: 1.1414x; 1.0313x over previous
//
#include <hip/hip_runtime.h>
#include <hip/hip_bf16.h>
#include <stdint.h>

// Problem constants
#define B_    2
#define S_    2048
#define H_    16
#define DH_   64
#define D_    1024
#define ND3   3072      // 3*D
#define MTOT  4096      // B*S
#define L2E   1.4426950408889634f
#define MASKVAL (-3.0e38f)   // causal mask: exp2(MASKVAL) == 0
#define SBIAS   (-14.0f)     // static softmax offset (log2 units)

typedef __attribute__((ext_vector_type(8))) short bf16x8;
typedef __attribute__((ext_vector_type(4))) short bf16x4;
typedef __attribute__((ext_vector_type(4))) float f32x4;

__device__ inline short f2bs(float f) {
  __hip_bfloat16 h = __float2bfloat16(f);
  return *reinterpret_cast<short*>(&h);
}

__device__ inline void gl_lds16(const void* g, void* l) {
  __builtin_amdgcn_global_load_lds(
      (const __attribute__((address_space(1))) uint32_t*)g,
      (__attribute__((address_space(3))) uint32_t*)l, 16, 0, 0);
}

// --------------------------------------- fused prep: x->bf16 and W->Wt bf16
__global__ __launch_bounds__(256) void prep_kernel(
    const float* __restrict__ X, const float* __restrict__ Wq,
    const float* __restrict__ Wk, const float* __restrict__ Wv,
    short* __restrict__ Xb, short* __restrict__ Wt) {
  __shared__ float t[32][33];
  int bid = blockIdx.x;
  if (bid < 4096) {
    const int i = (bid * 256 + threadIdx.x) * 4;
    float4 v = *reinterpret_cast<const float4*>(X + i);
    bf16x4 o;
    o[0] = f2bs(v.x); o[1] = f2bs(v.y); o[2] = f2bs(v.z); o[3] = f2bs(v.w);
    *reinterpret_cast<bf16x4*>(Xb + i) = o;
  } else {
    bid -= 4096;
    const int z = bid >> 10;             // 0..2 : Wq/Wk/Wv
    const int rem = bid & 1023;
    const int n0 = (rem & 31) * 32, k0 = (rem >> 5) * 32;
    const int x = threadIdx.x & 31, y = threadIdx.x >> 5;   // y in 0..7
    const float* W = z == 0 ? Wq : (z == 1 ? Wk : Wv);
    short* out = Wt + (size_t)z * (D_ * D_);
#pragma unroll
    for (int i = 0; i < 4; ++i)
      t[y + 8 * i][x] = W[(size_t)(k0 + y + 8 * i) * D_ + n0 + x];
    __syncthreads();
#pragma unroll
    for (int i = 0; i < 4; ++i)
      out[(size_t)(n0 + y + 8 * i) * D_ + k0 + x] = f2bs(t[x][y + 8 * i]);
  }
}

// ------------------------------------------------- QKV GEMM, 256x192 8-phase
// Grid 16x16 = 256 blocks = 1/CU. 512 threads (8 waves), BK=64, 16 K-tiles,
// LDS 112KB double-buffered. r16 change: ALL 7 staged pieces of tile j+1 are
// issued at P0 (4) and P1 (3) — the last piece now has ~2.5 phases to land
// before the single vmcnt(0) drain at P3-end (was 1 phase for B pieces).
// V epilogue writes Vt with an intra-64-kv PERMUTATION so the attention
// kernel can read V fragments as b128 pairs (see attn_kernel).
__global__ __launch_bounds__(512, 2) void qkv_gemm_kernel(
    const short* __restrict__ Xb, const short* __restrict__ Wt,
    const float* __restrict__ bq, const float* __restrict__ bk,
    const float* __restrict__ bv, short* __restrict__ QKV,
    short* __restrict__ Vt) {
  __shared__ char Lds[114688];   // buf d: A @ d*57344 (32KB), B @ +32768 (24KB)
  const int tid = threadIdx.x;
  const int lane = tid & 63;
  const int wid = tid >> 6;
  const int l15 = lane & 15, lg = lane >> 4;
  const int wm = wid >> 2, wn = wid & 3;
  // XCD-aware bijective swizzle (256 % 8 == 0)
  const int bid = blockIdx.x;
  const int wgid = (bid & 7) * 32 + (bid >> 3);
  const int m0 = (wgid >> 4) * 256, n0 = (wgid & 15) * 192;

  const int srow = tid >> 3;                         // 0..63
  const int scol = ((tid & 7) ^ (srow & 7)) * 8;
  const short* pa = Xb + (size_t)(m0 + srow) * D_ + scol;
  const short* pb = Wt + (size_t)(n0 + srow) * D_ + scol;
  char* sdst = Lds + (tid & 448) * 16;               // wave-uniform base

  const int abase = wm * 16384;                      // A rows wm*128..+127
  int a_off[8][2], b_off[3][2];
#pragma unroll
  for (int mr = 0; mr < 8; ++mr)
#pragma unroll
    for (int ks = 0; ks < 2; ++ks)
      a_off[mr][ks] =
          (mr * 16 + l15) * 128 + ((((ks * 4 + lg)) ^ (l15 & 7)) << 4);
#pragma unroll
  for (int nr = 0; nr < 3; ++nr)
#pragma unroll
    for (int ks = 0; ks < 2; ++ks)
      b_off[nr][ks] = (wn * 48 + nr * 16 + l15) * 128 +
                      ((((ks * 4 + lg)) ^ (l15 & 7)) << 4);

  f32x4 acc[8][3];
#pragma unroll
  for (int i = 0; i < 8; ++i)
#pragma unroll
    for (int j = 0; j < 3; ++j) acc[i][j] = (f32x4){0.f, 0.f, 0.f, 0.f};

#define BARRIER()                                                             \
  __builtin_amdgcn_s_barrier();                                               \
  __builtin_amdgcn_sched_barrier(0)

  // prologue: stage tile 0 fully into buf0
  gl_lds16(pa, sdst);
  gl_lds16(pa + (size_t)64 * D_, sdst + 8192);
  gl_lds16(pa + (size_t)128 * D_, sdst + 16384);
  gl_lds16(pa + (size_t)192 * D_, sdst + 24576);
  gl_lds16(pb, sdst + 32768);
  gl_lds16(pb + (size_t)64 * D_, sdst + 40960);
  gl_lds16(pb + (size_t)128 * D_, sdst + 49152);
  asm volatile("s_waitcnt vmcnt(0)" ::: "memory");
  BARRIER();

#define TILE(J, DL)                                                           \
  {                                                                           \
    const int j_ = (J);                                                       \
    const bool stg = (j_ + 1 < 16);                                           \
    const int RD = (DL) * 57344;                                              \
    const int WD = (1 - (DL)) * 57344;                                        \
    const short* pa1 = pa + (j_ + 1) * 64;                                    \
    const short* pb1 = pb + (j_ + 1) * 64;                                    \
    bf16x8 af[4], bf0, bf1, bf2;                                              \
    /* P0: stage A-lo + B0,B1; frags B ks0 + A ks0 mr0-3; MFMA acc[0..3] */   \
    if (stg) {                                                                \
      gl_lds16(pa1, sdst + WD);                                               \
      gl_lds16(pa1 + (size_t)64 * D_, sdst + WD + 8192);                      \
      gl_lds16(pb1, sdst + WD + 32768);                                       \
      gl_lds16(pb1 + (size_t)64 * D_, sdst + WD + 40960);                     \
    }                                                                         \
    bf0 = *reinterpret_cast<const bf16x8*>(Lds + RD + 32768 + b_off[0][0]);   \
    bf1 = *reinterpret_cast<const bf16x8*>(Lds + RD + 32768 + b_off[1][0]);   \
    bf2 = *reinterpret_cast<const bf16x8*>(Lds + RD + 32768 + b_off[2][0]);   \
    _Pragma("unroll") for (int mr = 0; mr < 4; ++mr) af[mr] =                 \
        *reinterpret_cast<const bf16x8*>(Lds + RD + abase + a_off[mr][0]);    \
    BARRIER();                                                                \
    __builtin_amdgcn_s_setprio(1);                                            \
    _Pragma("unroll") for (int mr = 0; mr < 4; ++mr) {                        \
      acc[mr][0] = __builtin_amdgcn_mfma_f32_16x16x32_bf16(af[mr], bf0,       \
                                                           acc[mr][0], 0, 0,  \
                                                           0);                \
      acc[mr][1] = __builtin_amdgcn_mfma_f32_16x16x32_bf16(af[mr], bf1,       \
                                                           acc[mr][1], 0, 0,  \
                                                           0);                \
      acc[mr][2] = __builtin_amdgcn_mfma_f32_16x16x32_bf16(af[mr], bf2,       \
                                                           acc[mr][2], 0, 0,  \
                                                           0);                \
    }                                                                         \
    __builtin_amdgcn_s_setprio(0);                                            \
    BARRIER();                                                                \
    /* P1: stage A-hi + B2; frags A ks0 mr4-7; MFMA acc[4..7] */              \
    if (stg) {                                                                \
      gl_lds16(pa1 + (size_t)128 * D_, sdst + WD + 16384);                    \
      gl_lds16(pa1 + (size_t)192 * D_, sdst + WD + 24576);                    \
      gl_lds16(pb1 + (size_t)128 * D_, sdst + WD + 49152);                    \
    }                                                                         \
    _Pragma("unroll") for (int mr = 0; mr < 4; ++mr) af[mr] =                 \
        *reinterpret_cast<const bf16x8*>(Lds + RD + abase +                   \
                                         a_off[mr + 4][0]);                   \
    BARRIER();                                                                \
    __builtin_amdgcn_s_setprio(1);                                            \
    _Pragma("unroll") for (int mr = 0; mr < 4; ++mr) {                        \
      acc[mr + 4][0] = __builtin_amdgcn_mfma_f32_16x16x32_bf16(               \
          af[mr], bf0, acc[mr + 4][0], 0, 0, 0);                              \
      acc[mr + 4][1] = __builtin_amdgcn_mfma_f32_16x16x32_bf16(               \
          af[mr], bf1, acc[mr + 4][1], 0, 0, 0);                              \
      acc[mr + 4][2] = __builtin_amdgcn_mfma_f32_16x16x32_bf16(               \
          af[mr], bf2, acc[mr + 4][2], 0, 0, 0);                              \
    }                                                                         \
    __builtin_amdgcn_s_setprio(0);                                            \
    BARRIER();                                                                \
    /* P2: frags B ks1 + A ks1 mr0-3; MFMA acc[0..3] */                       \
    bf0 = *reinterpret_cast<const bf16x8*>(Lds + RD + 32768 + b_off[0][1]);   \
    bf1 = *reinterpret_cast<const bf16x8*>(Lds + RD + 32768 + b_off[1][1]);   \
    bf2 = *reinterpret_cast<const bf16x8*>(Lds + RD + 32768 + b_off[2][1]);   \
    _Pragma("unroll") for (int mr = 0; mr < 4; ++mr) af[mr] =                 \
        *reinterpret_cast<const bf16x8*>(Lds + RD + abase + a_off[mr][1]);    \
    BARRIER();                                                                \
    __builtin_amdgcn_s_setprio(1);                                            \
    _Pragma("unroll") for (int mr = 0; mr < 4; ++mr) {                        \
      acc[mr][0] = __builtin_amdgcn_mfma_f32_16x16x32_bf16(af[mr], bf0,       \
                                                           acc[mr][0], 0, 0,  \
                                                           0);                \
      acc[mr][1] = __builtin_amdgcn_mfma_f32_16x16x32_bf16(af[mr], bf1,       \
                                                           acc[mr][1], 0, 0,  \
                                                           0);                \
      acc[mr][2] = __builtin_amdgcn_mfma_f32_16x16x32_bf16(af[mr], bf2,       \
                                                           acc[mr][2], 0, 0,  \
                                                           0);                \
    }                                                                         \
    __builtin_amdgcn_s_setprio(0);                                            \
    BARRIER();                                                                \
    /* P3: frags A ks1 mr4-7; MFMA acc[4..7]; drain staged loads */           \
    _Pragma("unroll") for (int mr = 0; mr < 4; ++mr) af[mr] =                 \
        *reinterpret_cast<const bf16x8*>(Lds + RD + abase +                   \
                                         a_off[mr + 4][1]);                   \
    BARRIER();                                                                \
    __builtin_amdgcn_s_setprio(1);                                            \
    _Pragma("unroll") for (int mr = 0; mr < 4; ++mr) {                        \
      acc[mr + 4][0] = __builtin_amdgcn_mfma_f32_16x16x32_bf16(               \
          af[mr], bf0, acc[mr + 4][0], 0, 0, 0);                              \
      acc[mr + 4][1] = __builtin_amdgcn_mfma_f32_16x16x32_bf16(               \
          af[mr], bf1, acc[mr + 4][1], 0, 0, 0);                              \
      acc[mr + 4][2] = __builtin_amdgcn_mfma_f32_16x16x32_bf16(               \
          af[mr], bf2, acc[mr + 4][2], 0, 0, 0);                              \
    }                                                                         \
    __builtin_amdgcn_s_setprio(0);                                            \
    asm volatile("s_waitcnt vmcnt(0)" ::: "memory");                          \
    BARRIER();                                                                \
  }

  for (int jj = 0; jj < 16; jj += 2) {
    TILE(jj, 0);
    TILE(jj + 1, 1);
  }
#undef TILE
#undef BARRIER

  // ---- epilogue (per-nr column branch; boundaries are multiples of 16) ----
  const int wr = wm * 128;
#pragma unroll
  for (int nr = 0; nr < 3; ++nr) {
    const int col = n0 + wn * 48 + nr * 16 + l15;
    if (col < 2 * D_) {  // Q or K -> qkv rows
      float bias, qs;
      if (col < D_) { bias = bq[col];      qs = 0.125f * L2E; }
      else          { bias = bk[col - D_]; qs = 1.f; }
#pragma unroll
      for (int mr = 0; mr < 8; ++mr)
#pragma unroll
        for (int r = 0; r < 4; ++r) {
          const int row = m0 + wr + mr * 16 + lg * 4 + r;
          QKV[(size_t)row * ND3 + col] = f2bs((acc[mr][nr][r] + bias) * qs);
        }
    } else {  // V -> Vt[bh][dh][s] with intra-64-kv PERMUTATION:
      // kv = 16*ntk + 4*lg + r stored at short-offset
      // ((ntk>>1)*4+lg)*8 + (ntk&1)*4 + r within its 64-kv tile, so the
      // attn kernel reads fragment PAIRS (ntk=2p, 2p+1) as one b128.
      const int f = col - 2 * D_;                    // v-feature 0..1023
      const float bias = bv[f];
      const int base0 = (m0 & 2047) + wr;            // multiple of 64
      short* vout = Vt + ((size_t)((m0 >> 11) * H_ + (f >> 6)) * DH_ +
                          (f & 63)) * S_;
#pragma unroll
      for (int mr = 0; mr < 8; ++mr) {
        bf16x4 pv;
#pragma unroll
        for (int r = 0; r < 4; ++r) pv[r] = f2bs(acc[mr][nr][r] + bias);
        const int ntk = mr & 3;
        const int s_new = base0 + (mr >> 2) * 64 +
                          ((ntk >> 1) * 4 + lg) * 8 + (ntk & 1) * 4;
        *reinterpret_cast<bf16x4*>(vout + s_new) = pv;
      }
    }
  }
}

// ----------------------------------------------------------- flash attention
// r16 = r12 structure with V fragments read as b128 PAIRS (8 ds_read_b128
// instead of 16 ds_read_b64 per wave-step) — the pair layout is baked into
// Vt by the GEMM V-epilogue, so V slot addressing becomes identical to K's
// ka[] formula. Everything else unchanged: static-offset softmax (SBIAS in
// the QK C-init), 2K+3V LDS slots (40KB), 4 blocks/CU, QK one tile ahead,
// raw barrier + vmcnt drain, XOR-swizzled staging, LPT order.
__global__ __launch_bounds__(256, 4) void attn_kernel(
    const short* __restrict__ QKV, const short* __restrict__ Vtg,
    float* __restrict__ Out) {
  __shared__ short KV[5][4096];   // 40KB: K slots @0,8192; V @16384/24576/32768
  const int tid = threadIdx.x;
  const int lane = tid & 63, wid = tid >> 6;
  const int l15 = lane & 15, lg = lane >> 4;
  const int bh = blockIdx.x;
  const int qt = (S_ / 64 - 1) - (int)blockIdx.y;   // LPT: longest first
  const int b = bh >> 4, h = bh & 15;
  const int q0 = qt * 64;
  const short* Qg = QKV + (size_t)b * S_ * ND3 + h * DH_;
  const short* Kg = QKV + (size_t)b * S_ * ND3 + D_ + h * DH_;
  const short* Vg = Vtg + (size_t)bh * DH_ * S_;

  const int srow = tid >> 3;
  const int scol = ((tid & 7) ^ (srow & 7)) * 8;
  const char* kbase = (const char*)&KV[0][0];
  char* dst = (char*)kbase + (tid & 192) * 16;
  int ka[2];
#pragma unroll
  for (int ks = 0; ks < 2; ++ks)
    ka[ks] = l15 * 128 + ((((ks * 4 + lg)) ^ (l15 & 7)) << 4);
  const int qrow_g = q0 + wid * 16 + l15;

  bf16x8 qf[2];
#pragma unroll
  for (int ks = 0; ks < 2; ++ks)
    qf[ks] = *reinterpret_cast<const bf16x8*>(Qg + (size_t)qrow_g * ND3 +
                                              ks * 32 + lg * 8);

  f32x4 o[4];
#pragma unroll
  for (int i = 0; i < 4; ++i) o[i] = (f32x4){0.f, 0.f, 0.f, 0.f};
  float lsum = 0.f;

  const short* kp = Kg + (size_t)srow * ND3 + scol;
  const short* vp = Vg + (size_t)srow * S_ + scol;

#define STAGE_AT(KOFF, VOFF)                                                  \
  {                                                                           \
    gl_lds16(kp, dst + (KOFF));                                               \
    gl_lds16(kp + 32 * ND3, dst + (KOFF) + 4096);                             \
    gl_lds16(vp, dst + (VOFF));                                               \
    gl_lds16(vp + 32 * S_, dst + (VOFF) + 4096);                              \
    kp += 64 * ND3;                                                           \
    vp += 64;                                                                 \
  }

  int kr = 8192, kw = 0;
  int vr = 16384, vw = 32768;          // VSUM = 73728

  STAGE_AT(0, 16384);
  if (qt >= 1) STAGE_AT(8192, 24576);
  asm volatile("s_waitcnt vmcnt(0)" ::: "memory");
  __builtin_amdgcn_s_barrier();
  __builtin_amdgcn_sched_barrier(0);

  f32x4 sA[4], sB[4];
#pragma unroll
  for (int i = 0; i < 4; ++i) sA[i] = (f32x4){SBIAS, SBIAS, SBIAS, SBIAS};
#pragma unroll
  for (int ks = 0; ks < 2; ++ks)
#pragma unroll
    for (int nt = 0; nt < 4; ++nt) {
      const bf16x8 kf =
          *reinterpret_cast<const bf16x8*>(kbase + ka[ks] + nt * 2048);
      sA[nt] = __builtin_amdgcn_mfma_f32_16x16x32_bf16(kf, qf[ks], sA[nt],
                                                       0, 0, 0);
    }

#define STEP_BODY(T, SC, SN)                                                  \
  {                                                                           \
    const int T_ = (T);                                                       \
    if (T_ + 2 <= qt) STAGE_AT(kw, vw);                                       \
    if (T_ + 1 <= qt) {                                                       \
      _Pragma("unroll") for (int i = 0; i < 4; ++i)                           \
          SN[i] = (f32x4){SBIAS, SBIAS, SBIAS, SBIAS};                        \
      _Pragma("unroll") for (int ks = 0; ks < 2; ++ks)                        \
        _Pragma("unroll") for (int nt = 0; nt < 4; ++nt) {                    \
          const bf16x8 kf = *reinterpret_cast<const bf16x8*>(                 \
              kbase + kr + ka[ks] + nt * 2048);                               \
          SN[nt] = __builtin_amdgcn_mfma_f32_16x16x32_bf16(kf, qf[ks],        \
                                                           SN[nt], 0, 0, 0);  \
        }                                                                     \
    }                                                                         \
    if (T_ == qt) { /* causal mask on diagonal tile */                        \
      const int kv0 = T_ * 64;                                                \
      _Pragma("unroll") for (int nt = 0; nt < 4; ++nt)                        \
        _Pragma("unroll") for (int r = 0; r < 4; ++r)                         \
          if (kv0 + nt * 16 + lg * 4 + r > qrow_g) SC[nt][r] = MASKVAL;       \
    }                                                                         \
    float rowsum = 0.f;                                                       \
    bf16x4 pk[4];                                                             \
    _Pragma("unroll") for (int nt = 0; nt < 4; ++nt) {                        \
      const float p0 = exp2f(SC[nt][0]);                                      \
      const float p1 = exp2f(SC[nt][1]);                                      \
      const float p2 = exp2f(SC[nt][2]);                                      \
      const float p3 = exp2f(SC[nt][3]);                                      \
      rowsum += (p0 + p1) + (p2 + p3);                                        \
      union { uint32_t u[2]; bf16x4 v; } pu;                                  \
      pu.u[0] = (__float_as_uint(p1) & 0xffff0000u) |                         \
                (__float_as_uint(p0) >> 16);                                  \
      pu.u[1] = (__float_as_uint(p3) & 0xffff0000u) |                         \
                (__float_as_uint(p2) >> 16);                                  \
      pk[nt] = pu.v;                                                          \
    }                                                                         \
    lsum += rowsum;                                                           \
    _Pragma("unroll") for (int p = 0; p < 2; ++p)                             \
      _Pragma("unroll") for (int ntd = 0; ntd < 4; ++ntd) {                   \
        const bf16x8 vf8 = *reinterpret_cast<const bf16x8*>(                  \
            kbase + vr + ka[p] + ntd * 2048);                                 \
        const bf16x4 vlo = __builtin_shufflevector(vf8, vf8, 0, 1, 2, 3);     \
        const bf16x4 vhi = __builtin_shufflevector(vf8, vf8, 4, 5, 6, 7);     \
        o[ntd] = __builtin_amdgcn_mfma_f32_16x16x16bf16_1k(vlo, pk[2 * p],    \
                                                           o[ntd], 0, 0, 0);  \
        o[ntd] = __builtin_amdgcn_mfma_f32_16x16x16bf16_1k(                   \
            vhi, pk[2 * p + 1], o[ntd], 0, 0, 0);                             \
      }                                                                       \
    if (T_ < qt) {                                                            \
      asm volatile("s_waitcnt vmcnt(0)" ::: "memory");                        \
      __builtin_amdgcn_s_barrier();                                           \
      __builtin_amdgcn_sched_barrier(0);                                      \
    }                                                                         \
    kr ^= 8192; kw ^= 8192;                                                   \
    { const int tv = vr; vr = 73728 - vr - vw; vw = tv; }                     \
  }

  for (int t = 0; t <= qt; t += 2) {
    STEP_BODY(t, sA, sB);
    if (t + 1 <= qt) STEP_BODY(t + 1, sB, sA);
  }
#undef STEP_BODY
#undef STAGE_AT

  float ls = lsum;
  ls += __shfl_xor(ls, 16);
  ls += __shfl_xor(ls, 32);
  const float inv = 1.f / ls;
#pragma unroll
  for (int nt = 0; nt < 4; ++nt) {
    f32x4 v = {o[nt][0] * inv, o[nt][1] * inv, o[nt][2] * inv, o[nt][3] * inv};
    *reinterpret_cast<f32x4*>(
        &Out[((size_t)b * S_ + qrow_g) * D_ + h * DH_ + nt * 16 + lg * 4]) = v;
  }
}

// ---------------------------------------------------------------- launcher
extern "C" void kernel_launch(void* const* d_in, const int* in_sizes, int n_in,
                              void* d_out, int out_size, void* d_ws,
                              size_t ws_size, hipStream_t stream) {
  const float* x  = (const float*)d_in[0];
  const float* Wq = (const float*)d_in[1];
  const float* bq = (const float*)d_in[2];
  const float* Wk = (const float*)d_in[3];
  const float* bk = (const float*)d_in[4];
  const float* Wv = (const float*)d_in[5];
  const float* bv = (const float*)d_in[6];
  float* out = (float*)d_out;

  char* ws = (char*)d_ws;
  short* xb  = (short*)(ws);             //  8 MB: [4096][1024] bf16
  short* Wt  = (short*)(ws + 8388608);   //  6 MB: [3072][1024] bf16
  short* qkv = (short*)(ws + 14680064);  // 24 MB: [4096][3072] bf16 (V unused)
  short* Vt  = (short*)(ws + 39845888);  //  8 MB: [32][64][2048] bf16 (kv-permuted)

  prep_kernel<<<dim3(4096 + 3072), dim3(256), 0, stream>>>(x, Wq, Wk, Wv, xb,
                                                           Wt);
  qkv_gemm_kernel<<<dim3(256), dim3(512), 0, stream>>>(xb, Wt, bq, bk, bv,
                                                       qkv, Vt);
  attn_kernel<<<dim3(B_ * H_, S_ / 64), dim3(256), 0, stream>>>(qkv, Vt, out);
}

// Round 17
// 69.691 us; speedup vs baseline: 1.2613x; 1.1050x over previous
//
#include <hip/hip_runtime.h>
#include <hip/hip_bf16.h>
#include <stdint.h>

// Problem constants
#define B_    2
#define S_    2048
#define H_    16
#define DH_   64
#define D_    1024
#define ND3   3072      // 3*D
#define MTOT  4096      // B*S
#define L2E   1.4426950408889634f
#define MASKVAL (-3.0e38f)   // causal mask: exp2(MASKVAL) == 0
#define SBIAS   (-14.0f)     // static softmax offset (log2 units)

typedef __attribute__((ext_vector_type(8))) short bf16x8;
typedef __attribute__((ext_vector_type(4))) short bf16x4;
typedef __attribute__((ext_vector_type(4))) float f32x4;

// raw v_exp_f32 (no OCML denormal fixup; exact for normal range, and
// exp2(-3e38) == 0 as required by the mask path)
#if __has_builtin(__builtin_amdgcn_exp2f)
#define EXP2(x) __builtin_amdgcn_exp2f(x)
#else
#define EXP2(x) exp2f(x)
#endif

__device__ inline short f2bs(float f) {
  __hip_bfloat16 h = __float2bfloat16(f);
  return *reinterpret_cast<short*>(&h);
}

__device__ inline void gl_lds16(const void* g, void* l) {
  __builtin_amdgcn_global_load_lds(
      (const __attribute__((address_space(1))) uint32_t*)g,
      (__attribute__((address_space(3))) uint32_t*)l, 16, 0, 0);
}

// --------------------------------------- fused prep: x->bf16 and W->Wt bf16
__global__ __launch_bounds__(256) void prep_kernel(
    const float* __restrict__ X, const float* __restrict__ Wq,
    const float* __restrict__ Wk, const float* __restrict__ Wv,
    short* __restrict__ Xb, short* __restrict__ Wt) {
  __shared__ float t[32][33];
  int bid = blockIdx.x;
  if (bid < 4096) {
    const int i = (bid * 256 + threadIdx.x) * 4;
    float4 v = *reinterpret_cast<const float4*>(X + i);
    bf16x4 o;
    o[0] = f2bs(v.x); o[1] = f2bs(v.y); o[2] = f2bs(v.z); o[3] = f2bs(v.w);
    *reinterpret_cast<bf16x4*>(Xb + i) = o;
  } else {
    bid -= 4096;
    const int z = bid >> 10;             // 0..2 : Wq/Wk/Wv
    const int rem = bid & 1023;
    const int n0 = (rem & 31) * 32, k0 = (rem >> 5) * 32;
    const int x = threadIdx.x & 31, y = threadIdx.x >> 5;   // y in 0..7
    const float* W = z == 0 ? Wq : (z == 1 ? Wk : Wv);
    short* out = Wt + (size_t)z * (D_ * D_);
#pragma unroll
    for (int i = 0; i < 4; ++i)
      t[y + 8 * i][x] = W[(size_t)(k0 + y + 8 * i) * D_ + n0 + x];
    __syncthreads();
#pragma unroll
    for (int i = 0; i < 4; ++i)
      out[(size_t)(n0 + y + 8 * i) * D_ + k0 + x] = f2bs(t[x][y + 8 * i]);
  }
}

// ------------------------------------------------- QKV GEMM, 256x192 8-phase
// (unchanged from r16 — 256 blocks = 1/CU, all 7 staged pieces at P0/P1,
// single vmcnt(0) drain at P3-end, V epilogue writes kv-permuted Vt)
__global__ __launch_bounds__(512, 2) void qkv_gemm_kernel(
    const short* __restrict__ Xb, const short* __restrict__ Wt,
    const float* __restrict__ bq, const float* __restrict__ bk,
    const float* __restrict__ bv, short* __restrict__ QKV,
    short* __restrict__ Vt) {
  __shared__ char Lds[114688];   // buf d: A @ d*57344 (32KB), B @ +32768 (24KB)
  const int tid = threadIdx.x;
  const int lane = tid & 63;
  const int wid = tid >> 6;
  const int l15 = lane & 15, lg = lane >> 4;
  const int wm = wid >> 2, wn = wid & 3;
  const int bid = blockIdx.x;
  const int wgid = (bid & 7) * 32 + (bid >> 3);
  const int m0 = (wgid >> 4) * 256, n0 = (wgid & 15) * 192;

  const int srow = tid >> 3;                         // 0..63
  const int scol = ((tid & 7) ^ (srow & 7)) * 8;
  const short* pa = Xb + (size_t)(m0 + srow) * D_ + scol;
  const short* pb = Wt + (size_t)(n0 + srow) * D_ + scol;
  char* sdst = Lds + (tid & 448) * 16;               // wave-uniform base

  const int abase = wm * 16384;                      // A rows wm*128..+127
  int a_off[8][2], b_off[3][2];
#pragma unroll
  for (int mr = 0; mr < 8; ++mr)
#pragma unroll
    for (int ks = 0; ks < 2; ++ks)
      a_off[mr][ks] =
          (mr * 16 + l15) * 128 + ((((ks * 4 + lg)) ^ (l15 & 7)) << 4);
#pragma unroll
  for (int nr = 0; nr < 3; ++nr)
#pragma unroll
    for (int ks = 0; ks < 2; ++ks)
      b_off[nr][ks] = (wn * 48 + nr * 16 + l15) * 128 +
                      ((((ks * 4 + lg)) ^ (l15 & 7)) << 4);

  f32x4 acc[8][3];
#pragma unroll
  for (int i = 0; i < 8; ++i)
#pragma unroll
    for (int j = 0; j < 3; ++j) acc[i][j] = (f32x4){0.f, 0.f, 0.f, 0.f};

#define BARRIER()                                                             \
  __builtin_amdgcn_s_barrier();                                               \
  __builtin_amdgcn_sched_barrier(0)

  gl_lds16(pa, sdst);
  gl_lds16(pa + (size_t)64 * D_, sdst + 8192);
  gl_lds16(pa + (size_t)128 * D_, sdst + 16384);
  gl_lds16(pa + (size_t)192 * D_, sdst + 24576);
  gl_lds16(pb, sdst + 32768);
  gl_lds16(pb + (size_t)64 * D_, sdst + 40960);
  gl_lds16(pb + (size_t)128 * D_, sdst + 49152);
  asm volatile("s_waitcnt vmcnt(0)" ::: "memory");
  BARRIER();

#define TILE(J, DL)                                                           \
  {                                                                           \
    const int j_ = (J);                                                       \
    const bool stg = (j_ + 1 < 16);                                           \
    const int RD = (DL) * 57344;                                              \
    const int WD = (1 - (DL)) * 57344;                                        \
    const short* pa1 = pa + (j_ + 1) * 64;                                    \
    const short* pb1 = pb + (j_ + 1) * 64;                                    \
    bf16x8 af[4], bf0, bf1, bf2;                                              \
    /* P0: stage A-lo + B0,B1; frags B ks0 + A ks0 mr0-3; MFMA acc[0..3] */   \
    if (stg) {                                                                \
      gl_lds16(pa1, sdst + WD);                                               \
      gl_lds16(pa1 + (size_t)64 * D_, sdst + WD + 8192);                      \
      gl_lds16(pb1, sdst + WD + 32768);                                       \
      gl_lds16(pb1 + (size_t)64 * D_, sdst + WD + 40960);                     \
    }                                                                         \
    bf0 = *reinterpret_cast<const bf16x8*>(Lds + RD + 32768 + b_off[0][0]);   \
    bf1 = *reinterpret_cast<const bf16x8*>(Lds + RD + 32768 + b_off[1][0]);   \
    bf2 = *reinterpret_cast<const bf16x8*>(Lds + RD + 32768 + b_off[2][0]);   \
    _Pragma("unroll") for (int mr = 0; mr < 4; ++mr) af[mr] =                 \
        *reinterpret_cast<const bf16x8*>(Lds + RD + abase + a_off[mr][0]);    \
    BARRIER();                                                                \
    __builtin_amdgcn_s_setprio(1);                                            \
    _Pragma("unroll") for (int mr = 0; mr < 4; ++mr) {                        \
      acc[mr][0] = __builtin_amdgcn_mfma_f32_16x16x32_bf16(af[mr], bf0,       \
                                                           acc[mr][0], 0, 0,  \
                                                           0);                \
      acc[mr][1] = __builtin_amdgcn_mfma_f32_16x16x32_bf16(af[mr], bf1,       \
                                                           acc[mr][1], 0, 0,  \
                                                           0);                \
      acc[mr][2] = __builtin_amdgcn_mfma_f32_16x16x32_bf16(af[mr], bf2,       \
                                                           acc[mr][2], 0, 0,  \
                                                           0);                \
    }                                                                         \
    __builtin_amdgcn_s_setprio(0);                                            \
    BARRIER();                                                                \
    /* P1: stage A-hi + B2; frags A ks0 mr4-7; MFMA acc[4..7] */              \
    if (stg) {                                                                \
      gl_lds16(pa1 + (size_t)128 * D_, sdst + WD + 16384);                    \
      gl_lds16(pa1 + (size_t)192 * D_, sdst + WD + 24576);                    \
      gl_lds16(pb1 + (size_t)128 * D_, sdst + WD + 49152);                    \
    }                                                                         \
    _Pragma("unroll") for (int mr = 0; mr < 4; ++mr) af[mr] =                 \
        *reinterpret_cast<const bf16x8*>(Lds + RD + abase +                   \
                                         a_off[mr + 4][0]);                   \
    BARRIER();                                                                \
    __builtin_amdgcn_s_setprio(1);                                            \
    _Pragma("unroll") for (int mr = 0; mr < 4; ++mr) {                        \
      acc[mr + 4][0] = __builtin_amdgcn_mfma_f32_16x16x32_bf16(               \
          af[mr], bf0, acc[mr + 4][0], 0, 0, 0);                              \
      acc[mr + 4][1] = __builtin_amdgcn_mfma_f32_16x16x32_bf16(               \
          af[mr], bf1, acc[mr + 4][1], 0, 0, 0);                              \
      acc[mr + 4][2] = __builtin_amdgcn_mfma_f32_16x16x32_bf16(               \
          af[mr], bf2, acc[mr + 4][2], 0, 0, 0);                              \
    }                                                                         \
    __builtin_amdgcn_s_setprio(0);                                            \
    BARRIER();                                                                \
    /* P2: frags B ks1 + A ks1 mr0-3; MFMA acc[0..3] */                       \
    bf0 = *reinterpret_cast<const bf16x8*>(Lds + RD + 32768 + b_off[0][1]);   \
    bf1 = *reinterpret_cast<const bf16x8*>(Lds + RD + 32768 + b_off[1][1]);   \
    bf2 = *reinterpret_cast<const bf16x8*>(Lds + RD + 32768 + b_off[2][1]);   \
    _Pragma("unroll") for (int mr = 0; mr < 4; ++mr) af[mr] =                 \
        *reinterpret_cast<const bf16x8*>(Lds + RD + abase + a_off[mr][1]);    \
    BARRIER();                                                                \
    __builtin_amdgcn_s_setprio(1);                                            \
    _Pragma("unroll") for (int mr = 0; mr < 4; ++mr) {                        \
      acc[mr][0] = __builtin_amdgcn_mfma_f32_16x16x32_bf16(af[mr], bf0,       \
                                                           acc[mr][0], 0, 0,  \
                                                           0);                \
      acc[mr][1] = __builtin_amdgcn_mfma_f32_16x16x32_bf16(af[mr], bf1,       \
                                                           acc[mr][1], 0, 0,  \
                                                           0);                \
      acc[mr][2] = __builtin_amdgcn_mfma_f32_16x16x32_bf16(af[mr], bf2,       \
                                                           acc[mr][2], 0, 0,  \
                                                           0);                \
    }                                                                         \
    __builtin_amdgcn_s_setprio(0);                                            \
    BARRIER();                                                                \
    /* P3: frags A ks1 mr4-7; MFMA acc[4..7]; drain staged loads */           \
    _Pragma("unroll") for (int mr = 0; mr < 4; ++mr) af[mr] =                 \
        *reinterpret_cast<const bf16x8*>(Lds + RD + abase +                   \
                                         a_off[mr + 4][1]);                   \
    BARRIER();                                                                \
    __builtin_amdgcn_s_setprio(1);                                            \
    _Pragma("unroll") for (int mr = 0; mr < 4; ++mr) {                        \
      acc[mr + 4][0] = __builtin_amdgcn_mfma_f32_16x16x32_bf16(               \
          af[mr], bf0, acc[mr + 4][0], 0, 0, 0);                              \
      acc[mr + 4][1] = __builtin_amdgcn_mfma_f32_16x16x32_bf16(               \
          af[mr], bf1, acc[mr + 4][1], 0, 0, 0);                              \
      acc[mr + 4][2] = __builtin_amdgcn_mfma_f32_16x16x32_bf16(               \
          af[mr], bf2, acc[mr + 4][2], 0, 0, 0);                              \
    }                                                                         \
    __builtin_amdgcn_s_setprio(0);                                            \
    asm volatile("s_waitcnt vmcnt(0)" ::: "memory");                          \
    BARRIER();                                                                \
  }

  for (int jj = 0; jj < 16; jj += 2) {
    TILE(jj, 0);
    TILE(jj + 1, 1);
  }
#undef TILE
#undef BARRIER

  const int wr = wm * 128;
#pragma unroll
  for (int nr = 0; nr < 3; ++nr) {
    const int col = n0 + wn * 48 + nr * 16 + l15;
    if (col < 2 * D_) {  // Q or K -> qkv rows
      float bias, qs;
      if (col < D_) { bias = bq[col];      qs = 0.125f * L2E; }
      else          { bias = bk[col - D_]; qs = 1.f; }
#pragma unroll
      for (int mr = 0; mr < 8; ++mr)
#pragma unroll
        for (int r = 0; r < 4; ++r) {
          const int row = m0 + wr + mr * 16 + lg * 4 + r;
          QKV[(size_t)row * ND3 + col] = f2bs((acc[mr][nr][r] + bias) * qs);
        }
    } else {  // V -> Vt[bh][dh][s], kv-permuted for b128 pair reads in attn
      const int f = col - 2 * D_;                    // v-feature 0..1023
      const float bias = bv[f];
      const int base0 = (m0 & 2047) + wr;            // multiple of 64
      short* vout = Vt + ((size_t)((m0 >> 11) * H_ + (f >> 6)) * DH_ +
                          (f & 63)) * S_;
#pragma unroll
      for (int mr = 0; mr < 8; ++mr) {
        bf16x4 pv;
#pragma unroll
        for (int r = 0; r < 4; ++r) pv[r] = f2bs(acc[mr][nr][r] + bias);
        const int ntk = mr & 3;
        const int s_new = base0 + (mr >> 2) * 64 +
                          ((ntk >> 1) * 4 + lg) * 8 + (ntk & 1) * 4;
        *reinterpret_cast<bf16x4*>(vout + s_new) = pv;
      }
    }
  }
}

// ----------------------------------------------------------- flash attention
// r17 = r16 structure with three issue-count cuts:
//  - raw v_exp_f32 (EXP2 builtin) instead of OCML exp2f (drops the denormal
//    fixup, ~3-4 VALU per call x 16/step),
//  - QK C-init from a constant register (no 16 v_mov/step),
//  - P pack via v_perm_b32 builtin (1 op/word).
__global__ __launch_bounds__(256, 4) void attn_kernel(
    const short* __restrict__ QKV, const short* __restrict__ Vtg,
    float* __restrict__ Out) {
  __shared__ short KV[5][4096];   // 40KB: K slots @0,8192; V @16384/24576/32768
  const int tid = threadIdx.x;
  const int lane = tid & 63, wid = tid >> 6;
  const int l15 = lane & 15, lg = lane >> 4;
  const int bh = blockIdx.x;
  const int qt = (S_ / 64 - 1) - (int)blockIdx.y;   // LPT: longest first
  const int b = bh >> 4, h = bh & 15;
  const int q0 = qt * 64;
  const short* Qg = QKV + (size_t)b * S_ * ND3 + h * DH_;
  const short* Kg = QKV + (size_t)b * S_ * ND3 + D_ + h * DH_;
  const short* Vg = Vtg + (size_t)bh * DH_ * S_;

  const int srow = tid >> 3;
  const int scol = ((tid & 7) ^ (srow & 7)) * 8;
  const char* kbase = (const char*)&KV[0][0];
  char* dst = (char*)kbase + (tid & 192) * 16;
  int ka[2];
#pragma unroll
  for (int ks = 0; ks < 2; ++ks)
    ka[ks] = l15 * 128 + ((((ks * 4 + lg)) ^ (l15 & 7)) << 4);
  const int qrow_g = q0 + wid * 16 + l15;

  bf16x8 qf[2];
#pragma unroll
  for (int ks = 0; ks < 2; ++ks)
    qf[ks] = *reinterpret_cast<const bf16x8*>(Qg + (size_t)qrow_g * ND3 +
                                              ks * 32 + lg * 8);

  const f32x4 cinit = (f32x4){SBIAS, SBIAS, SBIAS, SBIAS};  // constant C reg

  f32x4 o[4];
#pragma unroll
  for (int i = 0; i < 4; ++i) o[i] = (f32x4){0.f, 0.f, 0.f, 0.f};
  float lsum = 0.f;

  const short* kp = Kg + (size_t)srow * ND3 + scol;
  const short* vp = Vg + (size_t)srow * S_ + scol;

#define STAGE_AT(KOFF, VOFF)                                                  \
  {                                                                           \
    gl_lds16(kp, dst + (KOFF));                                               \
    gl_lds16(kp + 32 * ND3, dst + (KOFF) + 4096);                             \
    gl_lds16(vp, dst + (VOFF));                                               \
    gl_lds16(vp + 32 * S_, dst + (VOFF) + 4096);                              \
    kp += 64 * ND3;                                                           \
    vp += 64;                                                                 \
  }

  int kr = 8192, kw = 0;
  int vr = 16384, vw = 32768;          // VSUM = 73728

  STAGE_AT(0, 16384);
  if (qt >= 1) STAGE_AT(8192, 24576);
  asm volatile("s_waitcnt vmcnt(0)" ::: "memory");
  __builtin_amdgcn_s_barrier();
  __builtin_amdgcn_sched_barrier(0);

  f32x4 sA[4], sB[4];
#pragma unroll
  for (int nt = 0; nt < 4; ++nt)
    sA[nt] = __builtin_amdgcn_mfma_f32_16x16x32_bf16(
        *reinterpret_cast<const bf16x8*>(kbase + ka[0] + nt * 2048), qf[0],
        cinit, 0, 0, 0);
#pragma unroll
  for (int nt = 0; nt < 4; ++nt)
    sA[nt] = __builtin_amdgcn_mfma_f32_16x16x32_bf16(
        *reinterpret_cast<const bf16x8*>(kbase + ka[1] + nt * 2048), qf[1],
        sA[nt], 0, 0, 0);

#define STEP_BODY(T, SC, SN)                                                  \
  {                                                                           \
    const int T_ = (T);                                                       \
    if (T_ + 2 <= qt) STAGE_AT(kw, vw);                                       \
    if (T_ + 1 <= qt) {                                                       \
      _Pragma("unroll") for (int nt = 0; nt < 4; ++nt)                        \
          SN[nt] = __builtin_amdgcn_mfma_f32_16x16x32_bf16(                   \
              *reinterpret_cast<const bf16x8*>(kbase + kr + ka[0] +           \
                                               nt * 2048),                    \
              qf[0], cinit, 0, 0, 0);                                         \
      _Pragma("unroll") for (int nt = 0; nt < 4; ++nt)                        \
          SN[nt] = __builtin_amdgcn_mfma_f32_16x16x32_bf16(                   \
              *reinterpret_cast<const bf16x8*>(kbase + kr + ka[1] +           \
                                               nt * 2048),                    \
              qf[1], SN[nt], 0, 0, 0);                                        \
    }                                                                         \
    if (T_ == qt) { /* causal mask on diagonal tile */                        \
      const int kv0 = T_ * 64;                                                \
      _Pragma("unroll") for (int nt = 0; nt < 4; ++nt)                        \
        _Pragma("unroll") for (int r = 0; r < 4; ++r)                         \
          if (kv0 + nt * 16 + lg * 4 + r > qrow_g) SC[nt][r] = MASKVAL;       \
    }                                                                         \
    float rowsum = 0.f;                                                       \
    bf16x4 pk[4];                                                             \
    _Pragma("unroll") for (int nt = 0; nt < 4; ++nt) {                        \
      const float p0 = EXP2(SC[nt][0]);                                       \
      const float p1 = EXP2(SC[nt][1]);                                       \
      const float p2 = EXP2(SC[nt][2]);                                       \
      const float p3 = EXP2(SC[nt][3]);                                       \
      rowsum += (p0 + p1) + (p2 + p3);                                        \
      union { uint32_t u[2]; bf16x4 v; } pu;                                  \
      pu.u[0] = __builtin_amdgcn_perm(__float_as_uint(p1),                    \
                                      __float_as_uint(p0), 0x07060302u);      \
      pu.u[1] = __builtin_amdgcn_perm(__float_as_uint(p3),                    \
                                      __float_as_uint(p2), 0x07060302u);      \
      pk[nt] = pu.v;                                                          \
    }                                                                         \
    lsum += rowsum;                                                           \
    _Pragma("unroll") for (int p = 0; p < 2; ++p)                             \
      _Pragma("unroll") for (int ntd = 0; ntd < 4; ++ntd) {                   \
        const bf16x8 vf8 = *reinterpret_cast<const bf16x8*>(                  \
            kbase + vr + ka[p] + ntd * 2048);                                 \
        const bf16x4 vlo = __builtin_shufflevector(vf8, vf8, 0, 1, 2, 3);     \
        const bf16x4 vhi = __builtin_shufflevector(vf8, vf8, 4, 5, 6, 7);     \
        o[ntd] = __builtin_amdgcn_mfma_f32_16x16x16bf16_1k(vlo, pk[2 * p],    \
                                                           o[ntd], 0, 0, 0);  \
        o[ntd] = __builtin_amdgcn_mfma_f32_16x16x16bf16_1k(                   \
            vhi, pk[2 * p + 1], o[ntd], 0, 0, 0);                             \
      }                                                                       \
    if (T_ < qt) {                                                            \
      asm volatile("s_waitcnt vmcnt(0)" ::: "memory");                        \
      __builtin_amdgcn_s_barrier();                                           \
      __builtin_amdgcn_sched_barrier(0);                                      \
    }                                                                         \
    kr ^= 8192; kw ^= 8192;                                                   \
    { const int tv = vr; vr = 73728 - vr - vw; vw = tv; }                     \
  }

  for (int t = 0; t <= qt; t += 2) {
    STEP_BODY(t, sA, sB);
    if (t + 1 <= qt) STEP_BODY(t + 1, sB, sA);
  }
#undef STEP_BODY
#undef STAGE_AT

  float ls = lsum;
  ls += __shfl_xor(ls, 16);
  ls += __shfl_xor(ls, 32);
  const float inv = 1.f / ls;
#pragma unroll
  for (int nt = 0; nt < 4; ++nt) {
    f32x4 v = {o[nt][0] * inv, o[nt][1] * inv, o[nt][2] * inv, o[nt][3] * inv};
    *reinterpret_cast<f32x4*>(
        &Out[((size_t)b * S_ + qrow_g) * D_ + h * DH_ + nt * 16 + lg * 4]) = v;
  }
}

// ---------------------------------------------------------------- launcher
extern "C" void kernel_launch(void* const* d_in, const int* in_sizes, int n_in,
                              void* d_out, int out_size, void* d_ws,
                              size_t ws_size, hipStream_t stream) {
  const float* x  = (const float*)d_in[0];
  const float* Wq = (const float*)d_in[1];
  const float* bq = (const float*)d_in[2];
  const float* Wk = (const float*)d_in[3];
  const float* bk = (const float*)d_in[4];
  const float* Wv = (const float*)d_in[5];
  const float* bv = (const float*)d_in[6];
  float* out = (float*)d_out;

  char* ws = (char*)d_ws;
  short* xb  = (short*)(ws);             //  8 MB: [4096][1024] bf16
  short* Wt  = (short*)(ws + 8388608);   //  6 MB: [3072][1024] bf16
  short* qkv = (short*)(ws + 14680064);  // 24 MB: [4096][3072] bf16 (V unused)
  short* Vt  = (short*)(ws + 39845888);  //  8 MB: [32][64][2048] bf16 (kv-permuted)

  prep_kernel<<<dim3(4096 + 3072), dim3(256), 0, stream>>>(x, Wq, Wk, Wv, xb,
                                                           Wt);
  qkv_gemm_kernel<<<dim3(256), dim3(512), 0, stream>>>(xb, Wt, bq, bk, bv,
                                                       qkv, Vt);
  attn_kernel<<<dim3(B_ * H_, S_ / 64), dim3(256), 0, stream>>>(qkv, Vt, out);
}